// Round 5
// baseline (3279.097 us; speedup 1.0000x reference)
//
#include <hip/hip_runtime.h>
#include <stdint.h>

#define TOKENS 8192
#define HDIM 1024
#define IDIM 4096
#define NEXP 8
#define MPAD 17408
#define MTILES 136

typedef float f32x4 __attribute__((ext_vector_type(4)));
typedef __bf16 bf16x8 __attribute__((ext_vector_type(8)));

static __device__ __forceinline__ uint16_t f2bf(float f) {
  uint32_t u = __builtin_bit_cast(uint32_t, f);
  return (uint16_t)((u + 0x7fffu + ((u >> 16) & 1u)) >> 16);
}
static __device__ __forceinline__ uint32_t pack2(float a, float b) {
  return (uint32_t)f2bf(a) | ((uint32_t)f2bf(b) << 16);
}
static __device__ __forceinline__ float bf2f(uint32_t h) {
  return __builtin_bit_cast(float, h << 16);
}
#define SWZ4(r) (((r) >> 1) & 3u)
static __device__ __forceinline__ void load_lds16(const void* g, void* l) {
  __builtin_amdgcn_global_load_lds(
      (const __attribute__((address_space(1))) uint32_t*)(uintptr_t)g,
      (__attribute__((address_space(3))) uint32_t*)(uintptr_t)l, 16, 0, 0);
}
static __device__ __forceinline__ bf16x8 rdfrag(const char* base, uint32_t row, uint32_t g) {
  return *(const bf16x8*)(base + row * 64 + ((g ^ SWZ4(row)) * 16));
}
#define WAITV(n) asm volatile("s_waitcnt vmcnt(" #n ")" ::: "memory")
#define WAITL0 asm volatile("s_waitcnt lgkmcnt(0)" ::: "memory")
#define BAR __builtin_amdgcn_s_barrier()
#define SCHEDB __builtin_amdgcn_sched_barrier(0)

// ---------------- router ----------------
__global__ __launch_bounds__(256) void router_kernel(
    const float* __restrict__ x, const float* __restrict__ rw,
    uint16_t* __restrict__ xb, float2* __restrict__ topw, int2* __restrict__ tope,
    int* __restrict__ cnt_slots, float* __restrict__ psum_slots, float* __restrict__ zsum_slots) {
  const int tid = threadIdx.x;
  const int lane = tid & 63, wid = tid >> 6;
  const int t = blockIdx.x * 4 + wid;

  const float* xrow = x + (size_t)t * HDIM + lane * 16;
  float xc[16];
#pragma unroll
  for (int i = 0; i < 4; ++i) {
    float4 v = *(const float4*)(xrow + i * 4);
    xc[i * 4 + 0] = fminf(fmaxf(v.x, -10.f), 10.f);
    xc[i * 4 + 1] = fminf(fmaxf(v.y, -10.f), 10.f);
    xc[i * 4 + 2] = fminf(fmaxf(v.z, -10.f), 10.f);
    xc[i * 4 + 3] = fminf(fmaxf(v.w, -10.f), 10.f);
  }
  uint4 o0, o1;
  o0.x = pack2(xc[0], xc[1]);   o0.y = pack2(xc[2], xc[3]);
  o0.z = pack2(xc[4], xc[5]);   o0.w = pack2(xc[6], xc[7]);
  o1.x = pack2(xc[8], xc[9]);   o1.y = pack2(xc[10], xc[11]);
  o1.z = pack2(xc[12], xc[13]); o1.w = pack2(xc[14], xc[15]);
  uint4* dst = (uint4*)(xb + (size_t)t * HDIM + lane * 16);
  dst[0] = o0; dst[1] = o1;

  float acc[8];
#pragma unroll
  for (int e = 0; e < 8; ++e) acc[e] = 0.f;
  const float* rwp = rw + (size_t)(lane * 16) * NEXP;
#pragma unroll
  for (int i = 0; i < 16; ++i) {
    float xi = xc[i];
    float4 a = *(const float4*)(rwp + i * 8);
    float4 b = *(const float4*)(rwp + i * 8 + 4);
    acc[0] += xi * a.x; acc[1] += xi * a.y; acc[2] += xi * a.z; acc[3] += xi * a.w;
    acc[4] += xi * b.x; acc[5] += xi * b.y; acc[6] += xi * b.z; acc[7] += xi * b.w;
  }
#pragma unroll
  for (int s = 1; s < 64; s <<= 1) {
#pragma unroll
    for (int e = 0; e < 8; ++e) acc[e] += __shfl_xor(acc[e], s);
  }

  __shared__ float sp[8]; __shared__ int sc[8]; __shared__ float sz;
  if (tid < 8) { sp[tid] = 0.f; sc[tid] = 0; }
  if (tid == 0) sz = 0.f;
  __syncthreads();

  if (lane == 0) {
    float mx = acc[0];
#pragma unroll
    for (int e = 1; e < 8; ++e) mx = fmaxf(mx, acc[e]);
    float p[8]; float s = 0.f;
#pragma unroll
    for (int e = 0; e < 8; ++e) { p[e] = expf(acc[e] - mx); s += p[e]; }
    float inv = 1.f / s;
#pragma unroll
    for (int e = 0; e < 8; ++e) p[e] *= inv;
    float lse = mx + logf(s);
    int e0 = 0; float b0 = p[0];
#pragma unroll
    for (int e = 1; e < 8; ++e) if (p[e] > b0) { b0 = p[e]; e0 = e; }
    int e1 = (e0 == 0) ? 1 : 0; float b1 = (e0 == 0) ? p[1] : p[0];
#pragma unroll
    for (int e = 0; e < 8; ++e) if (e != e0 && p[e] > b1) { b1 = p[e]; e1 = e; }
    float wn = 1.f / (b0 + b1);
    topw[t] = make_float2(b0 * wn, b1 * wn);
    tope[t] = make_int2(e0, e1);
#pragma unroll
    for (int e = 0; e < 8; ++e) atomicAdd(&sp[e], p[e]);
    atomicAdd(&sc[e0], 1); atomicAdd(&sc[e1], 1);
    atomicAdd(&sz, lse * lse);
  }
  __syncthreads();
  int slot = blockIdx.x & 63;
  if (tid < 8) {
    atomicAdd(&cnt_slots[slot * 8 + tid], sc[tid]);
    atomicAdd(&psum_slots[slot * 8 + tid], sp[tid]);
  }
  if (tid == 0) atomicAdd(&zsum_slots[slot], sz);
}

// ---------------- scan ----------------
__global__ void scan_kernel(const int* __restrict__ cnt_slots,
                            const float* __restrict__ psum_slots,
                            const float* __restrict__ zsum_slots,
                            int* __restrict__ seg, int* __restrict__ fill_cnt,
                            float* __restrict__ out_sc) {
  const int tid = threadIdx.x;
  __shared__ int c[8]; __shared__ float ps[8];
  if (tid < 8) {
    int s = 0; float f = 0.f;
    for (int k = 0; k < 64; ++k) { s += cnt_slots[k * 8 + tid]; f += psum_slots[k * 8 + tid]; }
    c[tid] = s; ps[tid] = f; fill_cnt[tid] = 0;
  }
  __syncthreads();
  if (tid == 0) {
    int off = 0;
    for (int e = 0; e < 8; ++e) { seg[e] = off; off += (c[e] + 127) & ~127; }
    seg[8] = off;
    float lb = 0.f;
    for (int e = 0; e < 8; ++e)
      lb += ((float)c[e] / (2.0f * (float)TOKENS)) * (ps[e] / (float)TOKENS);
    lb *= 0.001f * (float)NEXP;
    float z = 0.f;
    for (int k = 0; k < 64; ++k) z += zsum_slots[k];
    out_sc[0] = lb;
    out_sc[1] = z / (float)TOKENS;
  }
}

// ---------------- fill ----------------
__global__ __launch_bounds__(256) void fill_kernel(
    const int2* __restrict__ tope, const int* __restrict__ seg,
    int* __restrict__ fill_cnt, int* __restrict__ rowtok) {
  const int t = blockIdx.x * 256 + threadIdx.x;
  const int lane = threadIdx.x & 63;
  const int2 te = tope[t];
#pragma unroll
  for (int k = 0; k < 2; ++k) {
    const int e = k ? te.y : te.x;
    int pos = 0;
    for (int ee = 0; ee < 8; ++ee) {
      unsigned long long mask = __ballot(e == ee);
      if (e == ee) {
        unsigned long long below = mask & ((lane == 0) ? 0ull : (~0ull >> (64 - lane)));
        int nbelow = __popcll(below);
        int leader = __ffsll((unsigned long long)mask) - 1;
        int base = 0;
        if (lane == leader) base = atomicAdd(&fill_cnt[ee], __popcll(mask));
        base = __shfl(base, leader);
        pos = seg[ee] + base + nbelow;
      }
    }
    rowtok[pos] = t * 2 + k;
  }
}

// ---------------- convert: fp32 [R][C] -> bf16 transposed [C][R] ----------------
__global__ __launch_bounds__(256) void convert_kernel(
    const float* __restrict__ w_gate, const float* __restrict__ w_up,
    const float* __restrict__ w_down, uint16_t* __restrict__ wgT,
    uint16_t* __restrict__ wuT, uint16_t* __restrict__ wdT) {
  __shared__ uint64_t tt[64][17];
  const int tid = threadIdx.x;
  const int z = blockIdx.y;
  const int bx = blockIdx.x;
  const float* src; uint16_t* dst; int R, C, tr, tc;
  if (z < 16) {
    R = 1024; C = 4096; tr = bx >> 6; tc = bx & 63;
    int e = z & 7;
    src = (z < 8 ? w_gate : w_up) + (size_t)e * 1024 * 4096;
    dst = (z < 8 ? wgT : wuT) + (size_t)e * 1024 * 4096;
  } else {
    R = 4096; C = 1024; tr = bx >> 4; tc = bx & 15;
    int e = z - 16;
    src = w_down + (size_t)e * 4096 * 1024;
    dst = wdT + (size_t)e * 4096 * 1024;
  }
  const int i = tid >> 4, j = tid & 15;
  float4 v0 = *(const float4*)(src + (size_t)(tr * 64 + 4 * i + 0) * C + tc * 64 + 4 * j);
  float4 v1 = *(const float4*)(src + (size_t)(tr * 64 + 4 * i + 1) * C + tc * 64 + 4 * j);
  float4 v2 = *(const float4*)(src + (size_t)(tr * 64 + 4 * i + 2) * C + tc * 64 + 4 * j);
  float4 v3 = *(const float4*)(src + (size_t)(tr * 64 + 4 * i + 3) * C + tc * 64 + 4 * j);
  tt[4 * j + 0][i] = (uint64_t)pack2(v0.x, v1.x) | ((uint64_t)pack2(v2.x, v3.x) << 32);
  tt[4 * j + 1][i] = (uint64_t)pack2(v0.y, v1.y) | ((uint64_t)pack2(v2.y, v3.y) << 32);
  tt[4 * j + 2][i] = (uint64_t)pack2(v0.z, v1.z) | ((uint64_t)pack2(v2.z, v3.z) << 32);
  tt[4 * j + 3][i] = (uint64_t)pack2(v0.w, v1.w) | ((uint64_t)pack2(v2.w, v3.w) << 32);
  __syncthreads();
#pragma unroll
  for (int it = 0; it < 2; ++it) {
    int idx = it * 256 + tid;
    int c = idx >> 3, h = idx & 7;
    uint64_t a = tt[c][2 * h], b = tt[c][2 * h + 1];
    uint4 v;
    v.x = (uint32_t)a; v.y = (uint32_t)(a >> 32);
    v.z = (uint32_t)b; v.w = (uint32_t)(b >> 32);
    *(uint4*)(dst + (size_t)(tc * 64 + c) * R + tr * 64 + h * 8) = v;
  }
}

static __device__ __forceinline__ int xcd_swz(int b, int nwg) {
  int q = nwg >> 3, r = nwg & 7;
  int xcd = b & 7;
  int base = (xcd < r) ? xcd * (q + 1) : r * (q + 1) + (xcd - r) * q;
  return base + (b >> 3);
}

// ---------------- gemm1: h = silu(x@wg) * (x@wu); BK=32 depth-3 counted-vmcnt ----------------
__global__ __launch_bounds__(256, 2) void gemm1_kernel(
    const uint16_t* __restrict__ xb, const uint16_t* __restrict__ wgT,
    const uint16_t* __restrict__ wuT, const int* __restrict__ rowtok,
    const int* __restrict__ seg, uint16_t* __restrict__ hbuf, int mt0) {
  __shared__ __align__(16) char smem[73728];
  const int tid = threadIdx.x;
  const int lane = tid & 63, wid = tid >> 6;
  const int ct = (int)gridDim.y;
  const int b = (int)(blockIdx.y * gridDim.x + blockIdx.x);
  const int wg_lin = xcd_swz(b, 32 * ct);
  const int iblk = wg_lin / ct;
  const int mrel = wg_lin % ct;
  const int mtile = mt0 + mrel;
  const int row0 = mtile * 128;
  if (row0 >= seg[8]) return;
  int e = 0;
  while (row0 >= seg[e + 1]) ++e;
  const uint16_t* wgp = wgT + (size_t)e * HDIM * IDIM;
  const uint16_t* wup = wuT + (size_t)e * HDIM * IDIM;
  const int icol0 = iblk * 128;

  const uint32_t r0 = (uint32_t)(wid * 32 + (lane >> 2));
  const uint32_t r1 = r0 + 16;
  const uint32_t cc0 = ((lane & 3u) ^ SWZ4(r0)) * 16;
  const uint32_t cc1 = ((lane & 3u) ^ SWZ4(r1)) * 16;
  int rt0 = rowtok[row0 + r0]; int tok0 = (rt0 < 0) ? 0 : (rt0 >> 1);
  int rt1 = rowtok[row0 + r1]; int tok1 = (rt1 < 0) ? 0 : (rt1 >> 1);
  const uintptr_t a0 = (uintptr_t)(xb + (size_t)tok0 * HDIM) + cc0;
  const uintptr_t a1 = (uintptr_t)(xb + (size_t)tok1 * HDIM) + cc1;
  const uintptr_t g0 = (uintptr_t)(wgp + (size_t)(icol0 + r0) * HDIM) + cc0;
  const uintptr_t g1 = (uintptr_t)(wgp + (size_t)(icol0 + r1) * HDIM) + cc1;
  const uintptr_t u0 = (uintptr_t)(wup + (size_t)(icol0 + r0) * HDIM) + cc0;
  const uintptr_t u1 = (uintptr_t)(wup + (size_t)(icol0 + r1) * HDIM) + cc1;
  const uint32_t ldsA = (uint32_t)(wid * 2048);

  f32x4 accg[4][4] = {}; f32x4 accu[4][4] = {};

#define G1_ISSUE(t, buf)                                                        \
  {                                                                             \
    char* B_ = smem + (buf) * 24576;                                            \
    size_t o_ = (size_t)(t) * 64;                                               \
    load_lds16((const void*)(a0 + o_), B_ + ldsA);                              \
    load_lds16((const void*)(a1 + o_), B_ + ldsA + 1024);                       \
    load_lds16((const void*)(g0 + o_), B_ + 8192 + ldsA);                       \
    load_lds16((const void*)(g1 + o_), B_ + 8192 + ldsA + 1024);                \
    load_lds16((const void*)(u0 + o_), B_ + 16384 + ldsA);                      \
    load_lds16((const void*)(u1 + o_), B_ + 16384 + ldsA + 1024);               \
  }

  const uint32_t g = lane >> 4, l15 = lane & 15;
  const uint32_t mrow = (uint32_t)((wid >> 1) * 64) + l15;
  const uint32_t nrow = (uint32_t)((wid & 1) * 64) + l15;

#define G1_PHASE(buf, DOISS, tt)                                                \
  {                                                                             \
    const char* B_ = smem + (buf) * 24576;                                      \
    bf16x8 af[4], bg[4], bu[4];                                                 \
    _Pragma("unroll") for (int mi = 0; mi < 4; ++mi)                            \
        af[mi] = rdfrag(B_, mrow + mi * 16, g);                                 \
    _Pragma("unroll") for (int ni = 0; ni < 4; ++ni) {                          \
      bg[ni] = rdfrag(B_ + 8192, nrow + ni * 16, g);                            \
      bu[ni] = rdfrag(B_ + 16384, nrow + ni * 16, g);                           \
    }                                                                           \
    WAITL0; SCHEDB;                                                             \
    BAR; SCHEDB;                                                                \
    if (DOISS) { G1_ISSUE(tt, buf); }                                           \
    SCHEDB;                                                                     \
    __builtin_amdgcn_s_setprio(1);                                              \
    _Pragma("unroll") for (int mi = 0; mi < 4; ++mi)                            \
        _Pragma("unroll") for (int ni = 0; ni < 4; ++ni) {                      \
      accg[mi][ni] = __builtin_amdgcn_mfma_f32_16x16x32_bf16(af[mi], bg[ni], accg[mi][ni], 0, 0, 0); \
      accu[mi][ni] = __builtin_amdgcn_mfma_f32_16x16x32_bf16(af[mi], bu[ni], accu[mi][ni], 0, 0, 0); \
    }                                                                           \
    __builtin_amdgcn_s_setprio(0);                                              \
  }

  const int NT = HDIM / 32;  // 32
  WAITV(0);
  G1_ISSUE(0, 0);
  G1_ISSUE(1, 1);
  G1_ISSUE(2, 2);
  int bsel = 0;
  for (int t = 0; t < NT - 3; ++t) {
    WAITV(12); BAR; SCHEDB;
    if (bsel == 0) { G1_PHASE(0, 1, t + 3); }
    else if (bsel == 1) { G1_PHASE(1, 1, t + 3); }
    else { G1_PHASE(2, 1, t + 3); }
    bsel = (bsel == 2) ? 0 : (bsel + 1);
  }
  WAITV(12); BAR; SCHEDB; G1_PHASE(2, 0, 0);
  WAITV(6);  BAR; SCHEDB; G1_PHASE(0, 0, 0);
  WAITV(0);  BAR; SCHEDB; G1_PHASE(1, 0, 0);

  __syncthreads();
  uint16_t* epi = (uint16_t*)smem;
  const int wr = wid >> 1, wc = wid & 1;
#pragma unroll
  for (int mi = 0; mi < 4; ++mi)
#pragma unroll
    for (int ni = 0; ni < 4; ++ni)
#pragma unroll
      for (int r = 0; r < 4; ++r) {
        float gv = accg[mi][ni][r], uv = accu[mi][ni][r];
        float hv = gv * uv * __frcp_rn(1.0f + __expf(-gv));
        int m = wr * 64 + mi * 16 + (lane >> 4) * 4 + r;
        int n = wc * 64 + ni * 16 + (lane & 15);
        epi[m * 136 + n] = f2bf(hv);
      }
  __syncthreads();
  const int hrow0 = (mtile - mt0) * 128;
  const int m = tid >> 1;
#pragma unroll
  for (int j = 0; j < 8; ++j) {
    int ch = (tid & 1) + j * 2;
    uint4 v = *(const uint4*)(smem + m * 272 + ch * 16);
    *(uint4*)(hbuf + ((size_t)(hrow0 + m)) * IDIM + icol0 + ch * 8) = v;
  }
}

// ---------------- gemm2: pair = h @ wd; BK=32 depth-3 counted-vmcnt ----------------
__global__ __launch_bounds__(256, 2) void gemm2_kernel(
    const uint16_t* __restrict__ hbuf, const uint16_t* __restrict__ wdT,
    const int* __restrict__ rowtok, const int* __restrict__ seg,
    uint16_t* __restrict__ pairbuf, int mt0) {
  __shared__ __align__(16) char smem[49152];
  const int tid = threadIdx.x;
  const int lane = tid & 63, wid = tid >> 6;
  const int ct = (int)gridDim.y;
  const int b = (int)(blockIdx.y * gridDim.x + blockIdx.x);
  const int wg_lin = xcd_swz(b, 8 * ct);
  const int nblk = wg_lin / ct;
  const int mrel = wg_lin % ct;
  const int mtile = mt0 + mrel;
  const int row0 = mtile * 128;
  if (row0 >= seg[8]) return;
  int e = 0;
  while (row0 >= seg[e + 1]) ++e;
  const uint16_t* wdp = wdT + (size_t)e * IDIM * HDIM;
  const int ncol0 = nblk * 128;
  const int hrow0 = (mtile - mt0) * 128;

  const uint32_t r0 = (uint32_t)(wid * 32 + (lane >> 2));
  const uint32_t r1 = r0 + 16;
  const uint32_t cc0 = ((lane & 3u) ^ SWZ4(r0)) * 16;
  const uint32_t cc1 = ((lane & 3u) ^ SWZ4(r1)) * 16;
  const uintptr_t a0 = (uintptr_t)(hbuf + (size_t)(hrow0 + r0) * IDIM) + cc0;
  const uintptr_t a1 = (uintptr_t)(hbuf + (size_t)(hrow0 + r1) * IDIM) + cc1;
  const uintptr_t b0 = (uintptr_t)(wdp + (size_t)(ncol0 + r0) * IDIM) + cc0;
  const uintptr_t b1 = (uintptr_t)(wdp + (size_t)(ncol0 + r1) * IDIM) + cc1;
  const uint32_t ldsA = (uint32_t)(wid * 2048);

  f32x4 acc[4][4] = {};

#define G2_ISSUE(t, buf)                                                        \
  {                                                                             \
    char* B_ = smem + (buf) * 16384;                                            \
    size_t o_ = (size_t)(t) * 64;                                               \
    load_lds16((const void*)(a0 + o_), B_ + ldsA);                              \
    load_lds16((const void*)(a1 + o_), B_ + ldsA + 1024);                       \
    load_lds16((const void*)(b0 + o_), B_ + 8192 + ldsA);                       \
    load_lds16((const void*)(b1 + o_), B_ + 8192 + ldsA + 1024);                \
  }

  const uint32_t g = lane >> 4, l15 = lane & 15;
  const uint32_t mrow = (uint32_t)((wid >> 1) * 64) + l15;
  const uint32_t nrow = (uint32_t)((wid & 1) * 64) + l15;

#define G2_PHASE(buf, DOISS, tt)                                                \
  {                                                                             \
    const char* B_ = smem + (buf) * 16384;                                      \
    bf16x8 af[4], bf[4];                                                        \
    _Pragma("unroll") for (int mi = 0; mi < 4; ++mi)                            \
        af[mi] = rdfrag(B_, mrow + mi * 16, g);                                 \
    _Pragma("unroll") for (int ni = 0; ni < 4; ++ni)                            \
        bf[ni] = rdfrag(B_ + 8192, nrow + ni * 16, g);                          \
    WAITL0; SCHEDB;                                                             \
    BAR; SCHEDB;                                                                \
    if (DOISS) { G2_ISSUE(tt, buf); }                                           \
    SCHEDB;                                                                     \
    __builtin_amdgcn_s_setprio(1);                                              \
    _Pragma("unroll") for (int mi = 0; mi < 4; ++mi)                            \
        _Pragma("unroll") for (int ni = 0; ni < 4; ++ni)                        \
            acc[mi][ni] = __builtin_amdgcn_mfma_f32_16x16x32_bf16(af[mi], bf[ni], acc[mi][ni], 0, 0, 0); \
    __builtin_amdgcn_s_setprio(0);                                              \
  }

  const int NT = IDIM / 32;  // 128
  WAITV(0);
  G2_ISSUE(0, 0);
  G2_ISSUE(1, 1);
  G2_ISSUE(2, 2);
  int bsel = 0;
  for (int t = 0; t < NT - 3; ++t) {
    WAITV(8); BAR; SCHEDB;
    if (bsel == 0) { G2_PHASE(0, 1, t + 3); }
    else if (bsel == 1) { G2_PHASE(1, 1, t + 3); }
    else { G2_PHASE(2, 1, t + 3); }
    bsel = (bsel == 2) ? 0 : (bsel + 1);
  }
  WAITV(8); BAR; SCHEDB; G2_PHASE(2, 0, 0);
  WAITV(4); BAR; SCHEDB; G2_PHASE(0, 0, 0);
  WAITV(0); BAR; SCHEDB; G2_PHASE(1, 0, 0);

  __syncthreads();
  uint16_t* epi = (uint16_t*)smem;
  const int wr = wid >> 1, wc = wid & 1;
#pragma unroll
  for (int mi = 0; mi < 4; ++mi)
#pragma unroll
    for (int ni = 0; ni < 4; ++ni)
#pragma unroll
      for (int r = 0; r < 4; ++r) {
        int m = wr * 64 + mi * 16 + (lane >> 4) * 4 + r;
        int n = wc * 64 + ni * 16 + (lane & 15);
        epi[m * 136 + n] = f2bf(acc[mi][ni][r]);
      }
  __syncthreads();
  const int m = tid >> 1;
  const int rt = rowtok[row0 + m];
  if (rt >= 0) {
#pragma unroll
    for (int j = 0; j < 8; ++j) {
      int ch = (tid & 1) + j * 2;
      uint4 v = *(const uint4*)(smem + m * 272 + ch * 16);
      *(uint4*)(pairbuf + (size_t)rt * HDIM + ncol0 + ch * 8) = v;
    }
  }
}

// ---------------- combine ----------------
__global__ __launch_bounds__(256) void combine_kernel(
    const uint16_t* __restrict__ pairbuf, const float2* __restrict__ topw,
    float* __restrict__ out) {
  size_t i = (size_t)blockIdx.x * 256 + threadIdx.x;
  int t = (int)(i >> 7);
  int ch = (int)(i & 127);
  float2 w = topw[t];
  const uint16_t* p0 = pairbuf + (size_t)(t * 2) * HDIM + ch * 8;
  uint4 a = *(const uint4*)p0;
  uint4 b = *(const uint4*)(p0 + HDIM);
  float o[8];
  uint32_t au[4] = {a.x, a.y, a.z, a.w};
  uint32_t bu[4] = {b.x, b.y, b.z, b.w};
#pragma unroll
  for (int j = 0; j < 4; ++j) {
    float v0 = w.x * bf2f(au[j] & 0xffffu) + w.y * bf2f(bu[j] & 0xffffu);
    float v1 = w.x * bf2f(au[j] >> 16) + w.y * bf2f(bu[j] >> 16);
    o[j * 2 + 0] = fminf(fmaxf(v0, -10.f), 10.f);
    o[j * 2 + 1] = fminf(fmaxf(v1, -10.f), 10.f);
  }
  float* op = out + (size_t)t * HDIM + ch * 8;
  float4 w0 = {o[0], o[1], o[2], o[3]};
  float4 w1 = {o[4], o[5], o[6], o[7]};
  *(float4*)op = w0;
  *(float4*)(op + 4) = w1;
}

extern "C" void kernel_launch(void* const* d_in, const int* in_sizes, int n_in,
                              void* d_out, int out_size, void* d_ws, size_t ws_size,
                              hipStream_t stream) {
  (void)in_sizes; (void)n_in; (void)out_size;
  const float* x = (const float*)d_in[0];
  const float* rw = (const float*)d_in[1];
  const float* w_gate = (const float*)d_in[2];
  const float* w_up = (const float*)d_in[3];
  const float* w_down = (const float*)d_in[4];
  float* out = (float*)d_out;

  char* ws = (char*)d_ws;
  size_t off = 0;
  auto alloc = [&](size_t n) { char* p = ws + off; off += (n + 255) & ~(size_t)255; return p; };
  uint16_t* xb = (uint16_t*)alloc((size_t)TOKENS * HDIM * 2);
  float2* topw = (float2*)alloc((size_t)TOKENS * 8);
  int2* tope = (int2*)alloc((size_t)TOKENS * 8);
  int* rowtok = (int*)alloc((size_t)MPAD * 4);
  int* seg = (int*)alloc(16 * 4);
  int* fill_cnt = (int*)alloc(8 * 4);
  int* cnt_slots = (int*)alloc(64 * 8 * 4);
  float* psum_slots = (float*)alloc(64 * 8 * 4);
  float* zsum_slots = (float*)alloc(64 * 4);
  uint16_t* pairbuf = (uint16_t*)alloc((size_t)TOKENS * 2 * HDIM * 2);
  uint16_t* wgT = (uint16_t*)alloc((size_t)NEXP * HDIM * IDIM * 2);
  uint16_t* wuT = (uint16_t*)alloc((size_t)NEXP * HDIM * IDIM * 2);
  uint16_t* wdT = (uint16_t*)alloc((size_t)NEXP * IDIM * HDIM * 2);
  uint16_t* hbuf = (uint16_t*)(ws + off);
  size_t avail = (ws_size > off) ? (ws_size - off) : 0;
  long tiles_fit = (long)(avail / (128ull * IDIM * 2));
  // chunk=32: hbuf chunk (32 MB) + active weight panels stay L3-resident,
  // preventing the weight re-fetch churn seen at chunk=136 (FETCH 567 MB vs 144 ideal)
  int chunk = (int)((tiles_fit < 1) ? 1 : (tiles_fit > 32 ? 32 : tiles_fit));

  hipMemsetAsync(cnt_slots, 0, 64 * 8 * 4, stream);
  hipMemsetAsync(psum_slots, 0, 64 * 8 * 4, stream);
  hipMemsetAsync(zsum_slots, 0, 64 * 4, stream);
  hipMemsetAsync(rowtok, 0xFF, (size_t)MPAD * 4, stream);

  convert_kernel<<<dim3(1024, 24), 256, 0, stream>>>(w_gate, w_up, w_down, wgT, wuT, wdT);
  router_kernel<<<TOKENS / 4, 256, 0, stream>>>(x, rw, xb, topw, tope,
                                                cnt_slots, psum_slots, zsum_slots);
  scan_kernel<<<1, 64, 0, stream>>>(cnt_slots, psum_slots, zsum_slots, seg, fill_cnt,
                                    out + (size_t)TOKENS * HDIM);
  fill_kernel<<<TOKENS / 256, 256, 0, stream>>>(tope, seg, fill_cnt, rowtok);

  for (int mt0 = 0; mt0 < MTILES; mt0 += chunk) {
    int ct = (MTILES - mt0 < chunk) ? (MTILES - mt0) : chunk;
    gemm1_kernel<<<dim3(IDIM / 128, ct), 256, 0, stream>>>(xb, wgT, wuT, rowtok, seg, hbuf, mt0);
    gemm2_kernel<<<dim3(HDIM / 128, ct), 256, 0, stream>>>(hbuf, wdT, rowtok, seg, pairbuf, mt0);
  }
  combine_kernel<<<(TOKENS * HDIM / 8) / 256, 256, 0, stream>>>(pairbuf, topw, out);
}

// Round 6
// 847.264 us; speedup vs baseline: 3.8702x; 3.8702x over previous
//
#include <hip/hip_runtime.h>
#include <stdint.h>

#define TOKENS 8192
#define HDIM 1024
#define IDIM 4096
#define NEXP 8
#define MPAD 17408
#define MTILES 136

typedef float f32x4 __attribute__((ext_vector_type(4)));
typedef __bf16 bf16x8 __attribute__((ext_vector_type(8)));

static __device__ __forceinline__ uint16_t f2bf(float f) {
  uint32_t u = __builtin_bit_cast(uint32_t, f);
  return (uint16_t)((u + 0x7fffu + ((u >> 16) & 1u)) >> 16);
}
static __device__ __forceinline__ uint32_t pack2(float a, float b) {
  return (uint32_t)f2bf(a) | ((uint32_t)f2bf(b) << 16);
}
static __device__ __forceinline__ float bf2f(uint32_t h) {
  return __builtin_bit_cast(float, h << 16);
}
#define SWZ4(r) (((r) >> 1) & 3u)
static __device__ __forceinline__ void load_lds16(const void* g, void* l) {
  __builtin_amdgcn_global_load_lds(
      (const __attribute__((address_space(1))) uint32_t*)(uintptr_t)g,
      (__attribute__((address_space(3))) uint32_t*)(uintptr_t)l, 16, 0, 0);
}
static __device__ __forceinline__ bf16x8 rdfrag(const char* base, uint32_t row, uint32_t g) {
  return *(const bf16x8*)(base + row * 64 + ((g ^ SWZ4(row)) * 16));
}
#define WAITV(n) asm volatile("s_waitcnt vmcnt(" #n ")" ::: "memory")
#define WAITL0 asm volatile("s_waitcnt lgkmcnt(0)" ::: "memory")
#define BAR __builtin_amdgcn_s_barrier()
#define SCHEDB __builtin_amdgcn_sched_barrier(0)

// ---------------- router ----------------
__global__ __launch_bounds__(256) void router_kernel(
    const float* __restrict__ x, const float* __restrict__ rw,
    uint16_t* __restrict__ xb, float2* __restrict__ topw, int2* __restrict__ tope,
    int* __restrict__ cnt_slots, float* __restrict__ psum_slots, float* __restrict__ zsum_slots) {
  const int tid = threadIdx.x;
  const int lane = tid & 63, wid = tid >> 6;
  const int t = blockIdx.x * 4 + wid;

  const float* xrow = x + (size_t)t * HDIM + lane * 16;
  float xc[16];
#pragma unroll
  for (int i = 0; i < 4; ++i) {
    float4 v = *(const float4*)(xrow + i * 4);
    xc[i * 4 + 0] = fminf(fmaxf(v.x, -10.f), 10.f);
    xc[i * 4 + 1] = fminf(fmaxf(v.y, -10.f), 10.f);
    xc[i * 4 + 2] = fminf(fmaxf(v.z, -10.f), 10.f);
    xc[i * 4 + 3] = fminf(fmaxf(v.w, -10.f), 10.f);
  }
  uint4 o0, o1;
  o0.x = pack2(xc[0], xc[1]);   o0.y = pack2(xc[2], xc[3]);
  o0.z = pack2(xc[4], xc[5]);   o0.w = pack2(xc[6], xc[7]);
  o1.x = pack2(xc[8], xc[9]);   o1.y = pack2(xc[10], xc[11]);
  o1.z = pack2(xc[12], xc[13]); o1.w = pack2(xc[14], xc[15]);
  uint4* dst = (uint4*)(xb + (size_t)t * HDIM + lane * 16);
  dst[0] = o0; dst[1] = o1;

  float acc[8];
#pragma unroll
  for (int e = 0; e < 8; ++e) acc[e] = 0.f;
  const float* rwp = rw + (size_t)(lane * 16) * NEXP;
#pragma unroll
  for (int i = 0; i < 16; ++i) {
    float xi = xc[i];
    float4 a = *(const float4*)(rwp + i * 8);
    float4 b = *(const float4*)(rwp + i * 8 + 4);
    acc[0] += xi * a.x; acc[1] += xi * a.y; acc[2] += xi * a.z; acc[3] += xi * a.w;
    acc[4] += xi * b.x; acc[5] += xi * b.y; acc[6] += xi * b.z; acc[7] += xi * b.w;
  }
#pragma unroll
  for (int s = 1; s < 64; s <<= 1) {
#pragma unroll
    for (int e = 0; e < 8; ++e) acc[e] += __shfl_xor(acc[e], s);
  }

  __shared__ float sp[8]; __shared__ int sc[8]; __shared__ float sz;
  if (tid < 8) { sp[tid] = 0.f; sc[tid] = 0; }
  if (tid == 0) sz = 0.f;
  __syncthreads();

  if (lane == 0) {
    float mx = acc[0];
#pragma unroll
    for (int e = 1; e < 8; ++e) mx = fmaxf(mx, acc[e]);
    float p[8]; float s = 0.f;
#pragma unroll
    for (int e = 0; e < 8; ++e) { p[e] = expf(acc[e] - mx); s += p[e]; }
    float inv = 1.f / s;
#pragma unroll
    for (int e = 0; e < 8; ++e) p[e] *= inv;
    float lse = mx + logf(s);
    int e0 = 0; float b0 = p[0];
#pragma unroll
    for (int e = 1; e < 8; ++e) if (p[e] > b0) { b0 = p[e]; e0 = e; }
    int e1 = (e0 == 0) ? 1 : 0; float b1 = (e0 == 0) ? p[1] : p[0];
#pragma unroll
    for (int e = 0; e < 8; ++e) if (e != e0 && p[e] > b1) { b1 = p[e]; e1 = e; }
    float wn = 1.f / (b0 + b1);
    topw[t] = make_float2(b0 * wn, b1 * wn);
    tope[t] = make_int2(e0, e1);
#pragma unroll
    for (int e = 0; e < 8; ++e) atomicAdd(&sp[e], p[e]);
    atomicAdd(&sc[e0], 1); atomicAdd(&sc[e1], 1);
    atomicAdd(&sz, lse * lse);
  }
  __syncthreads();
  int slot = blockIdx.x & 63;
  if (tid < 8) {
    atomicAdd(&cnt_slots[slot * 8 + tid], sc[tid]);
    atomicAdd(&psum_slots[slot * 8 + tid], sp[tid]);
  }
  if (tid == 0) atomicAdd(&zsum_slots[slot], sz);
}

// ---------------- scan ----------------
__global__ void scan_kernel(const int* __restrict__ cnt_slots,
                            const float* __restrict__ psum_slots,
                            const float* __restrict__ zsum_slots,
                            int* __restrict__ seg, int* __restrict__ fill_cnt,
                            float* __restrict__ out_sc) {
  const int tid = threadIdx.x;
  __shared__ int c[8]; __shared__ float ps[8];
  if (tid < 8) {
    int s = 0; float f = 0.f;
    for (int k = 0; k < 64; ++k) { s += cnt_slots[k * 8 + tid]; f += psum_slots[k * 8 + tid]; }
    c[tid] = s; ps[tid] = f; fill_cnt[tid] = 0;
  }
  __syncthreads();
  if (tid == 0) {
    int off = 0;
    for (int e = 0; e < 8; ++e) { seg[e] = off; off += (c[e] + 127) & ~127; }
    seg[8] = off;
    float lb = 0.f;
    for (int e = 0; e < 8; ++e)
      lb += ((float)c[e] / (2.0f * (float)TOKENS)) * (ps[e] / (float)TOKENS);
    lb *= 0.001f * (float)NEXP;
    float z = 0.f;
    for (int k = 0; k < 64; ++k) z += zsum_slots[k];
    out_sc[0] = lb;
    out_sc[1] = z / (float)TOKENS;
  }
}

// ---------------- fill ----------------
__global__ __launch_bounds__(256) void fill_kernel(
    const int2* __restrict__ tope, const int* __restrict__ seg,
    int* __restrict__ fill_cnt, int* __restrict__ rowtok) {
  const int t = blockIdx.x * 256 + threadIdx.x;
  const int lane = threadIdx.x & 63;
  const int2 te = tope[t];
#pragma unroll
  for (int k = 0; k < 2; ++k) {
    const int e = k ? te.y : te.x;
    int pos = 0;
    for (int ee = 0; ee < 8; ++ee) {
      unsigned long long mask = __ballot(e == ee);
      if (e == ee) {
        unsigned long long below = mask & ((lane == 0) ? 0ull : (~0ull >> (64 - lane)));
        int nbelow = __popcll(below);
        int leader = __ffsll((unsigned long long)mask) - 1;
        int base = 0;
        if (lane == leader) base = atomicAdd(&fill_cnt[ee], __popcll(mask));
        base = __shfl(base, leader);
        pos = seg[ee] + base + nbelow;
      }
    }
    rowtok[pos] = t * 2 + k;
  }
}

// ---------------- convert: fp32 [R][C] -> bf16 transposed [C][R] ----------------
__global__ __launch_bounds__(256) void convert_kernel(
    const float* __restrict__ w_gate, const float* __restrict__ w_up,
    const float* __restrict__ w_down, uint16_t* __restrict__ wgT,
    uint16_t* __restrict__ wuT, uint16_t* __restrict__ wdT) {
  __shared__ uint64_t tt[64][17];
  const int tid = threadIdx.x;
  const int z = blockIdx.y;
  const int bx = blockIdx.x;
  const float* src; uint16_t* dst; int R, C, tr, tc;
  if (z < 16) {
    R = 1024; C = 4096; tr = bx >> 6; tc = bx & 63;
    int e = z & 7;
    src = (z < 8 ? w_gate : w_up) + (size_t)e * 1024 * 4096;
    dst = (z < 8 ? wgT : wuT) + (size_t)e * 1024 * 4096;
  } else {
    R = 4096; C = 1024; tr = bx >> 4; tc = bx & 15;
    int e = z - 16;
    src = w_down + (size_t)e * 4096 * 1024;
    dst = wdT + (size_t)e * 4096 * 1024;
  }
  const int i = tid >> 4, j = tid & 15;
  float4 v0 = *(const float4*)(src + (size_t)(tr * 64 + 4 * i + 0) * C + tc * 64 + 4 * j);
  float4 v1 = *(const float4*)(src + (size_t)(tr * 64 + 4 * i + 1) * C + tc * 64 + 4 * j);
  float4 v2 = *(const float4*)(src + (size_t)(tr * 64 + 4 * i + 2) * C + tc * 64 + 4 * j);
  float4 v3 = *(const float4*)(src + (size_t)(tr * 64 + 4 * i + 3) * C + tc * 64 + 4 * j);
  tt[4 * j + 0][i] = (uint64_t)pack2(v0.x, v1.x) | ((uint64_t)pack2(v2.x, v3.x) << 32);
  tt[4 * j + 1][i] = (uint64_t)pack2(v0.y, v1.y) | ((uint64_t)pack2(v2.y, v3.y) << 32);
  tt[4 * j + 2][i] = (uint64_t)pack2(v0.z, v1.z) | ((uint64_t)pack2(v2.z, v3.z) << 32);
  tt[4 * j + 3][i] = (uint64_t)pack2(v0.w, v1.w) | ((uint64_t)pack2(v2.w, v3.w) << 32);
  __syncthreads();
#pragma unroll
  for (int it = 0; it < 2; ++it) {
    int idx = it * 256 + tid;
    int c = idx >> 3, h = idx & 7;
    uint64_t a = tt[c][2 * h], b = tt[c][2 * h + 1];
    uint4 v;
    v.x = (uint32_t)a; v.y = (uint32_t)(a >> 32);
    v.z = (uint32_t)b; v.w = (uint32_t)(b >> 32);
    *(uint4*)(dst + (size_t)(tc * 64 + c) * R + tr * 64 + h * 8) = v;
  }
}

static __device__ __forceinline__ int xcd_swz(int b, int nwg) {
  int q = nwg >> 3, r = nwg & 7;
  int xcd = b & 7;
  int base = (xcd < r) ? xcd * (q + 1) : r * (q + 1) + (xcd - r) * q;
  return base + (b >> 3);
}

// ---------------- gemm1: h = silu(x@wg) * (x@wu); BK=32 depth-2 counted-vmcnt ----------------
__global__ __launch_bounds__(256, 2) void gemm1_kernel(
    const uint16_t* __restrict__ xb, const uint16_t* __restrict__ wgT,
    const uint16_t* __restrict__ wuT, const int* __restrict__ rowtok,
    const int* __restrict__ seg, uint16_t* __restrict__ hbuf, int mt0) {
  __shared__ __align__(16) char smem[49152];
  const int tid = threadIdx.x;
  const int lane = tid & 63, wid = tid >> 6;
  const int ct = (int)gridDim.y;
  const int b = (int)(blockIdx.y * gridDim.x + blockIdx.x);
  const int wg_lin = xcd_swz(b, 32 * ct);
  const int iblk = wg_lin / ct;
  const int mrel = wg_lin % ct;
  const int mtile = mt0 + mrel;
  const int row0 = mtile * 128;
  if (row0 >= seg[8]) return;
  int e = 0;
  while (row0 >= seg[e + 1]) ++e;
  const uint16_t* wgp = wgT + (size_t)e * HDIM * IDIM;
  const uint16_t* wup = wuT + (size_t)e * HDIM * IDIM;
  const int icol0 = iblk * 128;

  const uint32_t r0 = (uint32_t)(wid * 32 + (lane >> 2));
  const uint32_t r1 = r0 + 16;
  const uint32_t cc0 = ((lane & 3u) ^ SWZ4(r0)) * 16;
  const uint32_t cc1 = ((lane & 3u) ^ SWZ4(r1)) * 16;
  int rt0 = rowtok[row0 + r0]; int tok0 = (rt0 < 0) ? 0 : (rt0 >> 1);
  int rt1 = rowtok[row0 + r1]; int tok1 = (rt1 < 0) ? 0 : (rt1 >> 1);
  const uintptr_t a0 = (uintptr_t)(xb + (size_t)tok0 * HDIM) + cc0;
  const uintptr_t a1 = (uintptr_t)(xb + (size_t)tok1 * HDIM) + cc1;
  const uintptr_t g0 = (uintptr_t)(wgp + (size_t)(icol0 + r0) * HDIM) + cc0;
  const uintptr_t g1 = (uintptr_t)(wgp + (size_t)(icol0 + r1) * HDIM) + cc1;
  const uintptr_t u0 = (uintptr_t)(wup + (size_t)(icol0 + r0) * HDIM) + cc0;
  const uintptr_t u1 = (uintptr_t)(wup + (size_t)(icol0 + r1) * HDIM) + cc1;
  const uint32_t ldsA = (uint32_t)(wid * 2048);

  f32x4 accg[4][4] = {}; f32x4 accu[4][4] = {};

#define G1_ISSUE(t, buf)                                                        \
  {                                                                             \
    char* B_ = smem + (buf) * 24576;                                            \
    size_t o_ = (size_t)(t) * 64;                                               \
    load_lds16((const void*)(a0 + o_), B_ + ldsA);                              \
    load_lds16((const void*)(a1 + o_), B_ + ldsA + 1024);                       \
    load_lds16((const void*)(g0 + o_), B_ + 8192 + ldsA);                       \
    load_lds16((const void*)(g1 + o_), B_ + 8192 + ldsA + 1024);                \
    load_lds16((const void*)(u0 + o_), B_ + 16384 + ldsA);                      \
    load_lds16((const void*)(u1 + o_), B_ + 16384 + ldsA + 1024);               \
  }

  const uint32_t g = lane >> 4, l15 = lane & 15;
  const uint32_t mrow = (uint32_t)((wid >> 1) * 64) + l15;
  const uint32_t nrow = (uint32_t)((wid & 1) * 64) + l15;

#define G1_PHASE(buf)                                                           \
  {                                                                             \
    const char* B_ = smem + (buf) * 24576;                                      \
    bf16x8 af[4], bg[4], bu[4];                                                 \
    _Pragma("unroll") for (int mi = 0; mi < 4; ++mi)                            \
        af[mi] = rdfrag(B_, mrow + mi * 16, g);                                 \
    _Pragma("unroll") for (int ni = 0; ni < 4; ++ni) {                          \
      bg[ni] = rdfrag(B_ + 8192, nrow + ni * 16, g);                            \
      bu[ni] = rdfrag(B_ + 16384, nrow + ni * 16, g);                           \
    }                                                                           \
    WAITL0; SCHEDB;                                                             \
    BAR; SCHEDB;                                                                \
    ISSUE_NEXT;                                                                 \
    SCHEDB;                                                                     \
    __builtin_amdgcn_s_setprio(1);                                              \
    _Pragma("unroll") for (int mi = 0; mi < 4; ++mi)                            \
        _Pragma("unroll") for (int ni = 0; ni < 4; ++ni) {                      \
      accg[mi][ni] = __builtin_amdgcn_mfma_f32_16x16x32_bf16(af[mi], bg[ni], accg[mi][ni], 0, 0, 0); \
      accu[mi][ni] = __builtin_amdgcn_mfma_f32_16x16x32_bf16(af[mi], bu[ni], accu[mi][ni], 0, 0, 0); \
    }                                                                           \
    __builtin_amdgcn_s_setprio(0);                                              \
  }

  const int NT = HDIM / 32;  // 32
  WAITV(0);
  G1_ISSUE(0, 0);
  G1_ISSUE(1, 1);
  for (int t = 0; t < NT - 1; ++t) {
    WAITV(6); BAR; SCHEDB;
#define ISSUE_NEXT if (t + 2 < NT) G1_ISSUE(t + 2, t & 1)
    G1_PHASE(t & 1);
#undef ISSUE_NEXT
  }
  {
    WAITV(0); BAR; SCHEDB;
#define ISSUE_NEXT
    G1_PHASE((NT - 1) & 1);
#undef ISSUE_NEXT
  }

  __syncthreads();
  uint16_t* epi = (uint16_t*)smem;
  const int wr = wid >> 1, wc = wid & 1;
#pragma unroll
  for (int mi = 0; mi < 4; ++mi)
#pragma unroll
    for (int ni = 0; ni < 4; ++ni)
#pragma unroll
      for (int r = 0; r < 4; ++r) {
        float gv = accg[mi][ni][r], uv = accu[mi][ni][r];
        float hv = gv * uv * __frcp_rn(1.0f + __expf(-gv));
        int m = wr * 64 + mi * 16 + (lane >> 4) * 4 + r;
        int n = wc * 64 + ni * 16 + (lane & 15);
        epi[m * 136 + n] = f2bf(hv);
      }
  __syncthreads();
  const int hrow0 = (mtile - mt0) * 128;
  const int m = tid >> 1;
#pragma unroll
  for (int j = 0; j < 8; ++j) {
    int ch = (tid & 1) + j * 2;
    uint4 v = *(const uint4*)(smem + m * 272 + ch * 16);
    *(uint4*)(hbuf + ((size_t)(hrow0 + m)) * IDIM + icol0 + ch * 8) = v;
  }
}

// ---------------- gemm2: pair = h @ wd; BK=32 depth-2 counted-vmcnt ----------------
__global__ __launch_bounds__(256, 2) void gemm2_kernel(
    const uint16_t* __restrict__ hbuf, const uint16_t* __restrict__ wdT,
    const int* __restrict__ rowtok, const int* __restrict__ seg,
    uint16_t* __restrict__ pairbuf, int mt0) {
  __shared__ __align__(16) char smem[34816];
  const int tid = threadIdx.x;
  const int lane = tid & 63, wid = tid >> 6;
  const int ct = (int)gridDim.y;
  const int b = (int)(blockIdx.y * gridDim.x + blockIdx.x);
  const int wg_lin = xcd_swz(b, 8 * ct);
  const int nblk = wg_lin / ct;
  const int mrel = wg_lin % ct;
  const int mtile = mt0 + mrel;
  const int row0 = mtile * 128;
  if (row0 >= seg[8]) return;
  int e = 0;
  while (row0 >= seg[e + 1]) ++e;
  const uint16_t* wdp = wdT + (size_t)e * IDIM * HDIM;
  const int ncol0 = nblk * 128;
  const int hrow0 = (mtile - mt0) * 128;

  const uint32_t r0 = (uint32_t)(wid * 32 + (lane >> 2));
  const uint32_t r1 = r0 + 16;
  const uint32_t cc0 = ((lane & 3u) ^ SWZ4(r0)) * 16;
  const uint32_t cc1 = ((lane & 3u) ^ SWZ4(r1)) * 16;
  const uintptr_t a0 = (uintptr_t)(hbuf + (size_t)(hrow0 + r0) * IDIM) + cc0;
  const uintptr_t a1 = (uintptr_t)(hbuf + (size_t)(hrow0 + r1) * IDIM) + cc1;
  const uintptr_t b0 = (uintptr_t)(wdp + (size_t)(ncol0 + r0) * IDIM) + cc0;
  const uintptr_t b1 = (uintptr_t)(wdp + (size_t)(ncol0 + r1) * IDIM) + cc1;
  const uint32_t ldsA = (uint32_t)(wid * 2048);

  f32x4 acc[4][4] = {};

#define G2_ISSUE(t, buf)                                                        \
  {                                                                             \
    char* B_ = smem + (buf) * 16384;                                            \
    size_t o_ = (size_t)(t) * 64;                                               \
    load_lds16((const void*)(a0 + o_), B_ + ldsA);                              \
    load_lds16((const void*)(a1 + o_), B_ + ldsA + 1024);                       \
    load_lds16((const void*)(b0 + o_), B_ + 8192 + ldsA);                       \
    load_lds16((const void*)(b1 + o_), B_ + 8192 + ldsA + 1024);                \
  }

  const uint32_t g = lane >> 4, l15 = lane & 15;
  const uint32_t mrow = (uint32_t)((wid >> 1) * 64) + l15;
  const uint32_t nrow = (uint32_t)((wid & 1) * 64) + l15;

#define G2_PHASE(buf)                                                           \
  {                                                                             \
    const char* B_ = smem + (buf) * 16384;                                      \
    bf16x8 af[4], bf[4];                                                        \
    _Pragma("unroll") for (int mi = 0; mi < 4; ++mi)                            \
        af[mi] = rdfrag(B_, mrow + mi * 16, g);                                 \
    _Pragma("unroll") for (int ni = 0; ni < 4; ++ni)                            \
        bf[ni] = rdfrag(B_ + 8192, nrow + ni * 16, g);                          \
    WAITL0; SCHEDB;                                                             \
    BAR; SCHEDB;                                                                \
    ISSUE_NEXT;                                                                 \
    SCHEDB;                                                                     \
    __builtin_amdgcn_s_setprio(1);                                              \
    _Pragma("unroll") for (int mi = 0; mi < 4; ++mi)                            \
        _Pragma("unroll") for (int ni = 0; ni < 4; ++ni)                        \
            acc[mi][ni] = __builtin_amdgcn_mfma_f32_16x16x32_bf16(af[mi], bf[ni], acc[mi][ni], 0, 0, 0); \
    __builtin_amdgcn_s_setprio(0);                                              \
  }

  const int NT = IDIM / 32;  // 128
  WAITV(0);
  G2_ISSUE(0, 0);
  G2_ISSUE(1, 1);
  for (int t = 0; t < NT - 1; ++t) {
    WAITV(4); BAR; SCHEDB;
#define ISSUE_NEXT if (t + 2 < NT) G2_ISSUE(t + 2, t & 1)
    G2_PHASE(t & 1);
#undef ISSUE_NEXT
  }
  {
    WAITV(0); BAR; SCHEDB;
#define ISSUE_NEXT
    G2_PHASE((NT - 1) & 1);
#undef ISSUE_NEXT
  }

  __syncthreads();
  uint16_t* epi = (uint16_t*)smem;
  const int wr = wid >> 1, wc = wid & 1;
#pragma unroll
  for (int mi = 0; mi < 4; ++mi)
#pragma unroll
    for (int ni = 0; ni < 4; ++ni)
#pragma unroll
      for (int r = 0; r < 4; ++r) {
        int m = wr * 64 + mi * 16 + (lane >> 4) * 4 + r;
        int n = wc * 64 + ni * 16 + (lane & 15);
        epi[m * 136 + n] = f2bf(acc[mi][ni][r]);
      }
  __syncthreads();
  const int m = tid >> 1;
  const int rt = rowtok[row0 + m];
  if (rt >= 0) {
#pragma unroll
    for (int j = 0; j < 8; ++j) {
      int ch = (tid & 1) + j * 2;
      uint4 v = *(const uint4*)(smem + m * 272 + ch * 16);
      *(uint4*)(pairbuf + (size_t)rt * HDIM + ncol0 + ch * 8) = v;
    }
  }
}

// ---------------- combine ----------------
__global__ __launch_bounds__(256) void combine_kernel(
    const uint16_t* __restrict__ pairbuf, const float2* __restrict__ topw,
    float* __restrict__ out) {
  size_t i = (size_t)blockIdx.x * 256 + threadIdx.x;
  int t = (int)(i >> 7);
  int ch = (int)(i & 127);
  float2 w = topw[t];
  const uint16_t* p0 = pairbuf + (size_t)(t * 2) * HDIM + ch * 8;
  uint4 a = *(const uint4*)p0;
  uint4 b = *(const uint4*)(p0 + HDIM);
  float o[8];
  uint32_t au[4] = {a.x, a.y, a.z, a.w};
  uint32_t bu[4] = {b.x, b.y, b.z, b.w};
#pragma unroll
  for (int j = 0; j < 4; ++j) {
    float v0 = w.x * bf2f(au[j] & 0xffffu) + w.y * bf2f(bu[j] & 0xffffu);
    float v1 = w.x * bf2f(au[j] >> 16) + w.y * bf2f(bu[j] >> 16);
    o[j * 2 + 0] = fminf(fmaxf(v0, -10.f), 10.f);
    o[j * 2 + 1] = fminf(fmaxf(v1, -10.f), 10.f);
  }
  float* op = out + (size_t)t * HDIM + ch * 8;
  float4 w0 = {o[0], o[1], o[2], o[3]};
  float4 w1 = {o[4], o[5], o[6], o[7]};
  *(float4*)op = w0;
  *(float4*)(op + 4) = w1;
}

extern "C" void kernel_launch(void* const* d_in, const int* in_sizes, int n_in,
                              void* d_out, int out_size, void* d_ws, size_t ws_size,
                              hipStream_t stream) {
  (void)in_sizes; (void)n_in; (void)out_size;
  const float* x = (const float*)d_in[0];
  const float* rw = (const float*)d_in[1];
  const float* w_gate = (const float*)d_in[2];
  const float* w_up = (const float*)d_in[3];
  const float* w_down = (const float*)d_in[4];
  float* out = (float*)d_out;

  char* ws = (char*)d_ws;
  size_t off = 0;
  auto alloc = [&](size_t n) { char* p = ws + off; off += (n + 255) & ~(size_t)255; return p; };
  uint16_t* xb = (uint16_t*)alloc((size_t)TOKENS * HDIM * 2);
  float2* topw = (float2*)alloc((size_t)TOKENS * 8);
  int2* tope = (int2*)alloc((size_t)TOKENS * 8);
  int* rowtok = (int*)alloc((size_t)MPAD * 4);
  int* seg = (int*)alloc(16 * 4);
  int* fill_cnt = (int*)alloc(8 * 4);
  int* cnt_slots = (int*)alloc(64 * 8 * 4);
  float* psum_slots = (float*)alloc(64 * 8 * 4);
  float* zsum_slots = (float*)alloc(64 * 4);
  uint16_t* pairbuf = (uint16_t*)alloc((size_t)TOKENS * 2 * HDIM * 2);
  uint16_t* wgT = (uint16_t*)alloc((size_t)NEXP * HDIM * IDIM * 2);
  uint16_t* wuT = (uint16_t*)alloc((size_t)NEXP * HDIM * IDIM * 2);
  uint16_t* wdT = (uint16_t*)alloc((size_t)NEXP * IDIM * HDIM * 2);
  uint16_t* hbuf = (uint16_t*)(ws + off);
  size_t avail = (ws_size > off) ? (ws_size - off) : 0;
  long tiles_fit = (long)(avail / (128ull * IDIM * 2));
  // chunk=32: hbuf chunk (32 MB) + active weight panels (~60 MB) stay L3-resident,
  // preventing the weight re-fetch churn seen at chunk=136 (FETCH 567 MB vs 256 MB set)
  int chunk = (int)((tiles_fit < 1) ? 1 : (tiles_fit > 32 ? 32 : tiles_fit));

  hipMemsetAsync(cnt_slots, 0, 64 * 8 * 4, stream);
  hipMemsetAsync(psum_slots, 0, 64 * 8 * 4, stream);
  hipMemsetAsync(zsum_slots, 0, 64 * 4, stream);
  hipMemsetAsync(rowtok, 0xFF, (size_t)MPAD * 4, stream);

  convert_kernel<<<dim3(1024, 24), 256, 0, stream>>>(w_gate, w_up, w_down, wgT, wuT, wdT);
  router_kernel<<<TOKENS / 4, 256, 0, stream>>>(x, rw, xb, topw, tope,
                                                cnt_slots, psum_slots, zsum_slots);
  scan_kernel<<<1, 64, 0, stream>>>(cnt_slots, psum_slots, zsum_slots, seg, fill_cnt,
                                    out + (size_t)TOKENS * HDIM);
  fill_kernel<<<TOKENS / 256, 256, 0, stream>>>(tope, seg, fill_cnt, rowtok);

  for (int mt0 = 0; mt0 < MTILES; mt0 += chunk) {
    int ct = (MTILES - mt0 < chunk) ? (MTILES - mt0) : chunk;
    gemm1_kernel<<<dim3(IDIM / 128, ct), 256, 0, stream>>>(xb, wgT, wuT, rowtok, seg, hbuf, mt0);
    gemm2_kernel<<<dim3(HDIM / 128, ct), 256, 0, stream>>>(hbuf, wdT, rowtok, seg, pairbuf, mt0);
  }
  combine_kernel<<<(TOKENS * HDIM / 8) / 256, 256, 0, stream>>>(pairbuf, topw, out);
}

// Round 7
// 763.987 us; speedup vs baseline: 4.2921x; 1.1090x over previous
//
#include <hip/hip_runtime.h>
#include <stdint.h>

#define TOKENS 8192
#define HDIM 1024
#define IDIM 4096
#define NEXP 8
#define MPAD 17408
#define MTILES 136

typedef float f32x4 __attribute__((ext_vector_type(4)));
typedef __bf16 bf16x8 __attribute__((ext_vector_type(8)));
typedef uint32_t u32x4 __attribute__((ext_vector_type(4)));

static __device__ __forceinline__ uint16_t f2bf(float f) {
  uint32_t u = __builtin_bit_cast(uint32_t, f);
  return (uint16_t)((u + 0x7fffu + ((u >> 16) & 1u)) >> 16);
}
static __device__ __forceinline__ uint32_t pack2(float a, float b) {
  return (uint32_t)f2bf(a) | ((uint32_t)f2bf(b) << 16);
}
static __device__ __forceinline__ float bf2f(uint32_t h) {
  return __builtin_bit_cast(float, h << 16);
}
#define SWZ4(r) (((r) >> 1) & 3u)
static __device__ __forceinline__ void load_lds16(const void* g, void* l) {
  __builtin_amdgcn_global_load_lds(
      (const __attribute__((address_space(1))) uint32_t*)(uintptr_t)g,
      (__attribute__((address_space(3))) uint32_t*)(uintptr_t)l, 16, 0, 0);
}
static __device__ __forceinline__ bf16x8 rdfrag(const char* base, uint32_t row, uint32_t g) {
  return *(const bf16x8*)(base + row * 64 + ((g ^ SWZ4(row)) * 16));
}
static __device__ __forceinline__ void nt_store4(void* p, u32x4 v) {
  __builtin_nontemporal_store(v, (u32x4*)p);
}
#define WAITV(n) asm volatile("s_waitcnt vmcnt(" #n ")" ::: "memory")
#define WAITL0 asm volatile("s_waitcnt lgkmcnt(0)" ::: "memory")
#define BAR __builtin_amdgcn_s_barrier()
#define SCHEDB __builtin_amdgcn_sched_barrier(0)

// ---------------- router ----------------
__global__ __launch_bounds__(256) void router_kernel(
    const float* __restrict__ x, const float* __restrict__ rw,
    uint16_t* __restrict__ xb, float2* __restrict__ topw, int2* __restrict__ tope,
    int* __restrict__ cnt_slots, float* __restrict__ psum_slots, float* __restrict__ zsum_slots) {
  const int tid = threadIdx.x;
  const int lane = tid & 63, wid = tid >> 6;
  const int t = blockIdx.x * 4 + wid;

  const float* xrow = x + (size_t)t * HDIM + lane * 16;
  float xc[16];
#pragma unroll
  for (int i = 0; i < 4; ++i) {
    float4 v = *(const float4*)(xrow + i * 4);
    xc[i * 4 + 0] = fminf(fmaxf(v.x, -10.f), 10.f);
    xc[i * 4 + 1] = fminf(fmaxf(v.y, -10.f), 10.f);
    xc[i * 4 + 2] = fminf(fmaxf(v.z, -10.f), 10.f);
    xc[i * 4 + 3] = fminf(fmaxf(v.w, -10.f), 10.f);
  }
  uint4 o0, o1;
  o0.x = pack2(xc[0], xc[1]);   o0.y = pack2(xc[2], xc[3]);
  o0.z = pack2(xc[4], xc[5]);   o0.w = pack2(xc[6], xc[7]);
  o1.x = pack2(xc[8], xc[9]);   o1.y = pack2(xc[10], xc[11]);
  o1.z = pack2(xc[12], xc[13]); o1.w = pack2(xc[14], xc[15]);
  uint4* dst = (uint4*)(xb + (size_t)t * HDIM + lane * 16);
  dst[0] = o0; dst[1] = o1;

  float acc[8];
#pragma unroll
  for (int e = 0; e < 8; ++e) acc[e] = 0.f;
  const float* rwp = rw + (size_t)(lane * 16) * NEXP;
#pragma unroll
  for (int i = 0; i < 16; ++i) {
    float xi = xc[i];
    float4 a = *(const float4*)(rwp + i * 8);
    float4 b = *(const float4*)(rwp + i * 8 + 4);
    acc[0] += xi * a.x; acc[1] += xi * a.y; acc[2] += xi * a.z; acc[3] += xi * a.w;
    acc[4] += xi * b.x; acc[5] += xi * b.y; acc[6] += xi * b.z; acc[7] += xi * b.w;
  }
#pragma unroll
  for (int s = 1; s < 64; s <<= 1) {
#pragma unroll
    for (int e = 0; e < 8; ++e) acc[e] += __shfl_xor(acc[e], s);
  }

  __shared__ float sp[8]; __shared__ int sc[8]; __shared__ float sz;
  if (tid < 8) { sp[tid] = 0.f; sc[tid] = 0; }
  if (tid == 0) sz = 0.f;
  __syncthreads();

  if (lane == 0) {
    float mx = acc[0];
#pragma unroll
    for (int e = 1; e < 8; ++e) mx = fmaxf(mx, acc[e]);
    float p[8]; float s = 0.f;
#pragma unroll
    for (int e = 0; e < 8; ++e) { p[e] = expf(acc[e] - mx); s += p[e]; }
    float inv = 1.f / s;
#pragma unroll
    for (int e = 0; e < 8; ++e) p[e] *= inv;
    float lse = mx + logf(s);
    int e0 = 0; float b0 = p[0];
#pragma unroll
    for (int e = 1; e < 8; ++e) if (p[e] > b0) { b0 = p[e]; e0 = e; }
    int e1 = (e0 == 0) ? 1 : 0; float b1 = (e0 == 0) ? p[1] : p[0];
#pragma unroll
    for (int e = 0; e < 8; ++e) if (e != e0 && p[e] > b1) { b1 = p[e]; e1 = e; }
    float wn = 1.f / (b0 + b1);
    topw[t] = make_float2(b0 * wn, b1 * wn);
    tope[t] = make_int2(e0, e1);
#pragma unroll
    for (int e = 0; e < 8; ++e) atomicAdd(&sp[e], p[e]);
    atomicAdd(&sc[e0], 1); atomicAdd(&sc[e1], 1);
    atomicAdd(&sz, lse * lse);
  }
  __syncthreads();
  int slot = blockIdx.x & 63;
  if (tid < 8) {
    atomicAdd(&cnt_slots[slot * 8 + tid], sc[tid]);
    atomicAdd(&psum_slots[slot * 8 + tid], sp[tid]);
  }
  if (tid == 0) atomicAdd(&zsum_slots[slot], sz);
}

// ---------------- scan ----------------
__global__ void scan_kernel(const int* __restrict__ cnt_slots,
                            const float* __restrict__ psum_slots,
                            const float* __restrict__ zsum_slots,
                            int* __restrict__ seg, int* __restrict__ fill_cnt,
                            float* __restrict__ out_sc) {
  const int tid = threadIdx.x;
  __shared__ int c[8]; __shared__ float ps[8];
  if (tid < 8) {
    int s = 0; float f = 0.f;
    for (int k = 0; k < 64; ++k) { s += cnt_slots[k * 8 + tid]; f += psum_slots[k * 8 + tid]; }
    c[tid] = s; ps[tid] = f; fill_cnt[tid] = 0;
  }
  __syncthreads();
  if (tid == 0) {
    int off = 0;
    for (int e = 0; e < 8; ++e) { seg[e] = off; off += (c[e] + 127) & ~127; }
    seg[8] = off;
    float lb = 0.f;
    for (int e = 0; e < 8; ++e)
      lb += ((float)c[e] / (2.0f * (float)TOKENS)) * (ps[e] / (float)TOKENS);
    lb *= 0.001f * (float)NEXP;
    float z = 0.f;
    for (int k = 0; k < 64; ++k) z += zsum_slots[k];
    out_sc[0] = lb;
    out_sc[1] = z / (float)TOKENS;
  }
}

// ---------------- fill ----------------
__global__ __launch_bounds__(256) void fill_kernel(
    const int2* __restrict__ tope, const int* __restrict__ seg,
    int* __restrict__ fill_cnt, int* __restrict__ rowtok) {
  const int t = blockIdx.x * 256 + threadIdx.x;
  const int lane = threadIdx.x & 63;
  const int2 te = tope[t];
#pragma unroll
  for (int k = 0; k < 2; ++k) {
    const int e = k ? te.y : te.x;
    int pos = 0;
    for (int ee = 0; ee < 8; ++ee) {
      unsigned long long mask = __ballot(e == ee);
      if (e == ee) {
        unsigned long long below = mask & ((lane == 0) ? 0ull : (~0ull >> (64 - lane)));
        int nbelow = __popcll(below);
        int leader = __ffsll((unsigned long long)mask) - 1;
        int base = 0;
        if (lane == leader) base = atomicAdd(&fill_cnt[ee], __popcll(mask));
        base = __shfl(base, leader);
        pos = seg[ee] + base + nbelow;
      }
    }
    rowtok[pos] = t * 2 + k;
  }
}

// ---------------- convert: fp32 [R][C] -> bf16 transposed [C][R], NT streaming ----------------
__global__ __launch_bounds__(256) void convert_kernel(
    const float* __restrict__ w_gate, const float* __restrict__ w_up,
    const float* __restrict__ w_down, uint16_t* __restrict__ wgT,
    uint16_t* __restrict__ wuT, uint16_t* __restrict__ wdT) {
  __shared__ uint64_t tt[64][17];
  const int tid = threadIdx.x;
  const int z = blockIdx.y;
  const int bx = blockIdx.x;
  const float* src; uint16_t* dst; int R, C, tr, tc;
  if (z < 16) {
    R = 1024; C = 4096; tr = bx >> 6; tc = bx & 63;
    int e = z & 7;
    src = (z < 8 ? w_gate : w_up) + (size_t)e * 1024 * 4096;
    dst = (z < 8 ? wgT : wuT) + (size_t)e * 1024 * 4096;
  } else {
    R = 4096; C = 1024; tr = bx >> 4; tc = bx & 15;
    int e = z - 16;
    src = w_down + (size_t)e * 4096 * 1024;
    dst = wdT + (size_t)e * 4096 * 1024;
  }
  const int i = tid >> 4, j = tid & 15;
  f32x4 v0 = __builtin_nontemporal_load((const f32x4*)(src + (size_t)(tr * 64 + 4 * i + 0) * C + tc * 64 + 4 * j));
  f32x4 v1 = __builtin_nontemporal_load((const f32x4*)(src + (size_t)(tr * 64 + 4 * i + 1) * C + tc * 64 + 4 * j));
  f32x4 v2 = __builtin_nontemporal_load((const f32x4*)(src + (size_t)(tr * 64 + 4 * i + 2) * C + tc * 64 + 4 * j));
  f32x4 v3 = __builtin_nontemporal_load((const f32x4*)(src + (size_t)(tr * 64 + 4 * i + 3) * C + tc * 64 + 4 * j));
  tt[4 * j + 0][i] = (uint64_t)pack2(v0[0], v1[0]) | ((uint64_t)pack2(v2[0], v3[0]) << 32);
  tt[4 * j + 1][i] = (uint64_t)pack2(v0[1], v1[1]) | ((uint64_t)pack2(v2[1], v3[1]) << 32);
  tt[4 * j + 2][i] = (uint64_t)pack2(v0[2], v1[2]) | ((uint64_t)pack2(v2[2], v3[2]) << 32);
  tt[4 * j + 3][i] = (uint64_t)pack2(v0[3], v1[3]) | ((uint64_t)pack2(v2[3], v3[3]) << 32);
  __syncthreads();
#pragma unroll
  for (int it = 0; it < 2; ++it) {
    int idx = it * 256 + tid;
    int c = idx >> 3, h = idx & 7;
    uint64_t a = tt[c][2 * h], b = tt[c][2 * h + 1];
    u32x4 v;
    v[0] = (uint32_t)a; v[1] = (uint32_t)(a >> 32);
    v[2] = (uint32_t)b; v[3] = (uint32_t)(b >> 32);
    nt_store4(dst + (size_t)(tc * 64 + c) * R + tr * 64 + h * 8, v);
  }
}

static __device__ __forceinline__ int xcd_swz(int b, int nwg) {
  int q = nwg >> 3, r = nwg & 7;
  int xcd = b & 7;
  int base = (xcd < r) ? xcd * (q + 1) : r * (q + 1) + (xcd - r) * q;
  return base + (b >> 3);
}

// ---------------- gemm1: h = silu(x@wg) * (x@wu); BK=32 depth-2 counted-vmcnt ----------------
__global__ __launch_bounds__(256, 2) void gemm1_kernel(
    const uint16_t* __restrict__ xb, const uint16_t* __restrict__ wgT,
    const uint16_t* __restrict__ wuT, const int* __restrict__ rowtok,
    const int* __restrict__ seg, uint16_t* __restrict__ hbuf, int mt0) {
  __shared__ __align__(16) char smem[49152];
  const int tid = threadIdx.x;
  const int lane = tid & 63, wid = tid >> 6;
  const int ct = (int)gridDim.y;
  const int b = (int)(blockIdx.y * gridDim.x + blockIdx.x);
  const int wg_lin = xcd_swz(b, 32 * ct);
  const int iblk = wg_lin / ct;
  const int mrel = wg_lin % ct;
  const int mtile = mt0 + mrel;
  const int row0 = mtile * 128;
  if (row0 >= seg[8]) return;
  int e = 0;
  while (row0 >= seg[e + 1]) ++e;
  const uint16_t* wgp = wgT + (size_t)e * HDIM * IDIM;
  const uint16_t* wup = wuT + (size_t)e * HDIM * IDIM;
  const int icol0 = iblk * 128;

  const uint32_t r0 = (uint32_t)(wid * 32 + (lane >> 2));
  const uint32_t r1 = r0 + 16;
  const uint32_t cc0 = ((lane & 3u) ^ SWZ4(r0)) * 16;
  const uint32_t cc1 = ((lane & 3u) ^ SWZ4(r1)) * 16;
  int rt0 = rowtok[row0 + r0]; int tok0 = (rt0 < 0) ? 0 : (rt0 >> 1);
  int rt1 = rowtok[row0 + r1]; int tok1 = (rt1 < 0) ? 0 : (rt1 >> 1);
  const uintptr_t a0 = (uintptr_t)(xb + (size_t)tok0 * HDIM) + cc0;
  const uintptr_t a1 = (uintptr_t)(xb + (size_t)tok1 * HDIM) + cc1;
  const uintptr_t g0 = (uintptr_t)(wgp + (size_t)(icol0 + r0) * HDIM) + cc0;
  const uintptr_t g1 = (uintptr_t)(wgp + (size_t)(icol0 + r1) * HDIM) + cc1;
  const uintptr_t u0 = (uintptr_t)(wup + (size_t)(icol0 + r0) * HDIM) + cc0;
  const uintptr_t u1 = (uintptr_t)(wup + (size_t)(icol0 + r1) * HDIM) + cc1;
  const uint32_t ldsA = (uint32_t)(wid * 2048);

  f32x4 accg[4][4] = {}; f32x4 accu[4][4] = {};

#define G1_ISSUE(t, buf)                                                        \
  {                                                                             \
    char* B_ = smem + (buf) * 24576;                                            \
    size_t o_ = (size_t)(t) * 64;                                               \
    load_lds16((const void*)(a0 + o_), B_ + ldsA);                              \
    load_lds16((const void*)(a1 + o_), B_ + ldsA + 1024);                       \
    load_lds16((const void*)(g0 + o_), B_ + 8192 + ldsA);                       \
    load_lds16((const void*)(g1 + o_), B_ + 8192 + ldsA + 1024);                \
    load_lds16((const void*)(u0 + o_), B_ + 16384 + ldsA);                      \
    load_lds16((const void*)(u1 + o_), B_ + 16384 + ldsA + 1024);               \
  }

  const uint32_t g = lane >> 4, l15 = lane & 15;
  const uint32_t mrow = (uint32_t)((wid >> 1) * 64) + l15;
  const uint32_t nrow = (uint32_t)((wid & 1) * 64) + l15;

#define G1_PHASE(buf)                                                           \
  {                                                                             \
    const char* B_ = smem + (buf) * 24576;                                      \
    bf16x8 af[4], bg[4], bu[4];                                                 \
    _Pragma("unroll") for (int mi = 0; mi < 4; ++mi)                            \
        af[mi] = rdfrag(B_, mrow + mi * 16, g);                                 \
    _Pragma("unroll") for (int ni = 0; ni < 4; ++ni) {                          \
      bg[ni] = rdfrag(B_ + 8192, nrow + ni * 16, g);                            \
      bu[ni] = rdfrag(B_ + 16384, nrow + ni * 16, g);                           \
    }                                                                           \
    WAITL0; SCHEDB;                                                             \
    BAR; SCHEDB;                                                                \
    ISSUE_NEXT;                                                                 \
    SCHEDB;                                                                     \
    __builtin_amdgcn_s_setprio(1);                                              \
    _Pragma("unroll") for (int mi = 0; mi < 4; ++mi)                            \
        _Pragma("unroll") for (int ni = 0; ni < 4; ++ni) {                      \
      accg[mi][ni] = __builtin_amdgcn_mfma_f32_16x16x32_bf16(af[mi], bg[ni], accg[mi][ni], 0, 0, 0); \
      accu[mi][ni] = __builtin_amdgcn_mfma_f32_16x16x32_bf16(af[mi], bu[ni], accu[mi][ni], 0, 0, 0); \
    }                                                                           \
    __builtin_amdgcn_s_setprio(0);                                              \
  }

  const int NT = HDIM / 32;  // 32
  WAITV(0);
  G1_ISSUE(0, 0);
  G1_ISSUE(1, 1);
  for (int t = 0; t < NT - 1; ++t) {
    WAITV(6); BAR; SCHEDB;
#define ISSUE_NEXT if (t + 2 < NT) G1_ISSUE(t + 2, t & 1)
    G1_PHASE(t & 1);
#undef ISSUE_NEXT
  }
  {
    WAITV(0); BAR; SCHEDB;
#define ISSUE_NEXT
    G1_PHASE((NT - 1) & 1);
#undef ISSUE_NEXT
  }

  __syncthreads();
  uint16_t* epi = (uint16_t*)smem;
  const int wr = wid >> 1, wc = wid & 1;
#pragma unroll
  for (int mi = 0; mi < 4; ++mi)
#pragma unroll
    for (int ni = 0; ni < 4; ++ni)
#pragma unroll
      for (int r = 0; r < 4; ++r) {
        float gv = accg[mi][ni][r], uv = accu[mi][ni][r];
        float hv = gv * uv * __frcp_rn(1.0f + __expf(-gv));
        int m = wr * 64 + mi * 16 + (lane >> 4) * 4 + r;
        int n = wc * 64 + ni * 16 + (lane & 15);
        epi[m * 136 + n] = f2bf(hv);
      }
  __syncthreads();
  const int hrow0 = (mtile - mt0) * 128;
  const int m = tid >> 1;
#pragma unroll
  for (int j = 0; j < 8; ++j) {
    int ch = (tid & 1) + j * 2;
    u32x4 v = *(const u32x4*)(smem + m * 272 + ch * 16);
    nt_store4(hbuf + ((size_t)(hrow0 + m)) * IDIM + icol0 + ch * 8, v);
  }
}

// ---------------- gemm2: pair = h @ wd; BK=32 depth-2 counted-vmcnt ----------------
__global__ __launch_bounds__(256, 2) void gemm2_kernel(
    const uint16_t* __restrict__ hbuf, const uint16_t* __restrict__ wdT,
    const int* __restrict__ rowtok, const int* __restrict__ seg,
    uint16_t* __restrict__ pairbuf, int mt0) {
  __shared__ __align__(16) char smem[34816];
  const int tid = threadIdx.x;
  const int lane = tid & 63, wid = tid >> 6;
  const int ct = (int)gridDim.y;
  const int b = (int)(blockIdx.y * gridDim.x + blockIdx.x);
  const int wg_lin = xcd_swz(b, 8 * ct);
  const int nblk = wg_lin / ct;
  const int mrel = wg_lin % ct;
  const int mtile = mt0 + mrel;
  const int row0 = mtile * 128;
  if (row0 >= seg[8]) return;
  int e = 0;
  while (row0 >= seg[e + 1]) ++e;
  const uint16_t* wdp = wdT + (size_t)e * IDIM * HDIM;
  const int ncol0 = nblk * 128;
  const int hrow0 = (mtile - mt0) * 128;

  const uint32_t r0 = (uint32_t)(wid * 32 + (lane >> 2));
  const uint32_t r1 = r0 + 16;
  const uint32_t cc0 = ((lane & 3u) ^ SWZ4(r0)) * 16;
  const uint32_t cc1 = ((lane & 3u) ^ SWZ4(r1)) * 16;
  const uintptr_t a0 = (uintptr_t)(hbuf + (size_t)(hrow0 + r0) * IDIM) + cc0;
  const uintptr_t a1 = (uintptr_t)(hbuf + (size_t)(hrow0 + r1) * IDIM) + cc1;
  const uintptr_t b0 = (uintptr_t)(wdp + (size_t)(ncol0 + r0) * IDIM) + cc0;
  const uintptr_t b1 = (uintptr_t)(wdp + (size_t)(ncol0 + r1) * IDIM) + cc1;
  const uint32_t ldsA = (uint32_t)(wid * 2048);

  f32x4 acc[4][4] = {};

#define G2_ISSUE(t, buf)                                                        \
  {                                                                             \
    char* B_ = smem + (buf) * 16384;                                            \
    size_t o_ = (size_t)(t) * 64;                                               \
    load_lds16((const void*)(a0 + o_), B_ + ldsA);                              \
    load_lds16((const void*)(a1 + o_), B_ + ldsA + 1024);                       \
    load_lds16((const void*)(b0 + o_), B_ + 8192 + ldsA);                       \
    load_lds16((const void*)(b1 + o_), B_ + 8192 + ldsA + 1024);                \
  }

  const uint32_t g = lane >> 4, l15 = lane & 15;
  const uint32_t mrow = (uint32_t)((wid >> 1) * 64) + l15;
  const uint32_t nrow = (uint32_t)((wid & 1) * 64) + l15;

#define G2_PHASE(buf)                                                           \
  {                                                                             \
    const char* B_ = smem + (buf) * 16384;                                      \
    bf16x8 af[4], bf[4];                                                        \
    _Pragma("unroll") for (int mi = 0; mi < 4; ++mi)                            \
        af[mi] = rdfrag(B_, mrow + mi * 16, g);                                 \
    _Pragma("unroll") for (int ni = 0; ni < 4; ++ni)                            \
        bf[ni] = rdfrag(B_ + 8192, nrow + ni * 16, g);                          \
    WAITL0; SCHEDB;                                                             \
    BAR; SCHEDB;                                                                \
    ISSUE_NEXT;                                                                 \
    SCHEDB;                                                                     \
    __builtin_amdgcn_s_setprio(1);                                              \
    _Pragma("unroll") for (int mi = 0; mi < 4; ++mi)                            \
        _Pragma("unroll") for (int ni = 0; ni < 4; ++ni)                        \
            acc[mi][ni] = __builtin_amdgcn_mfma_f32_16x16x32_bf16(af[mi], bf[ni], acc[mi][ni], 0, 0, 0); \
    __builtin_amdgcn_s_setprio(0);                                              \
  }

  const int NT = IDIM / 32;  // 128
  WAITV(0);
  G2_ISSUE(0, 0);
  G2_ISSUE(1, 1);
  for (int t = 0; t < NT - 1; ++t) {
    WAITV(4); BAR; SCHEDB;
#define ISSUE_NEXT if (t + 2 < NT) G2_ISSUE(t + 2, t & 1)
    G2_PHASE(t & 1);
#undef ISSUE_NEXT
  }
  {
    WAITV(0); BAR; SCHEDB;
#define ISSUE_NEXT
    G2_PHASE((NT - 1) & 1);
#undef ISSUE_NEXT
  }

  __syncthreads();
  uint16_t* epi = (uint16_t*)smem;
  const int wr = wid >> 1, wc = wid & 1;
#pragma unroll
  for (int mi = 0; mi < 4; ++mi)
#pragma unroll
    for (int ni = 0; ni < 4; ++ni)
#pragma unroll
      for (int r = 0; r < 4; ++r) {
        int m = wr * 64 + mi * 16 + (lane >> 4) * 4 + r;
        int n = wc * 64 + ni * 16 + (lane & 15);
        epi[m * 136 + n] = f2bf(acc[mi][ni][r]);
      }
  __syncthreads();
  const int m = tid >> 1;
  const int rt = rowtok[row0 + m];
  if (rt >= 0) {
#pragma unroll
    for (int j = 0; j < 8; ++j) {
      int ch = (tid & 1) + j * 2;
      u32x4 v = *(const u32x4*)(smem + m * 272 + ch * 16);
      nt_store4(pairbuf + (size_t)rt * HDIM + ncol0 + ch * 8, v);
    }
  }
}

// ---------------- combine ----------------
__global__ __launch_bounds__(256) void combine_kernel(
    const uint16_t* __restrict__ pairbuf, const float2* __restrict__ topw,
    float* __restrict__ out) {
  size_t i = (size_t)blockIdx.x * 256 + threadIdx.x;
  int t = (int)(i >> 7);
  int ch = (int)(i & 127);
  float2 w = topw[t];
  const uint16_t* p0 = pairbuf + (size_t)(t * 2) * HDIM + ch * 8;
  uint4 a = *(const uint4*)p0;
  uint4 b = *(const uint4*)(p0 + HDIM);
  float o[8];
  uint32_t au[4] = {a.x, a.y, a.z, a.w};
  uint32_t bu[4] = {b.x, b.y, b.z, b.w};
#pragma unroll
  for (int j = 0; j < 4; ++j) {
    float v0 = w.x * bf2f(au[j] & 0xffffu) + w.y * bf2f(bu[j] & 0xffffu);
    float v1 = w.x * bf2f(au[j] >> 16) + w.y * bf2f(bu[j] >> 16);
    o[j * 2 + 0] = fminf(fmaxf(v0, -10.f), 10.f);
    o[j * 2 + 1] = fminf(fmaxf(v1, -10.f), 10.f);
  }
  float* op = out + (size_t)t * HDIM + ch * 8;
  float4 w0 = {o[0], o[1], o[2], o[3]};
  float4 w1 = {o[4], o[5], o[6], o[7]};
  *(float4*)op = w0;
  *(float4*)(op + 4) = w1;
}

extern "C" void kernel_launch(void* const* d_in, const int* in_sizes, int n_in,
                              void* d_out, int out_size, void* d_ws, size_t ws_size,
                              hipStream_t stream) {
  (void)in_sizes; (void)n_in; (void)out_size;
  const float* x = (const float*)d_in[0];
  const float* rw = (const float*)d_in[1];
  const float* w_gate = (const float*)d_in[2];
  const float* w_up = (const float*)d_in[3];
  const float* w_down = (const float*)d_in[4];
  float* out = (float*)d_out;

  char* ws = (char*)d_ws;
  size_t off = 0;
  auto alloc = [&](size_t n) { char* p = ws + off; off += (n + 255) & ~(size_t)255; return p; };
  uint16_t* xb = (uint16_t*)alloc((size_t)TOKENS * HDIM * 2);
  float2* topw = (float2*)alloc((size_t)TOKENS * 8);
  int2* tope = (int2*)alloc((size_t)TOKENS * 8);
  int* rowtok = (int*)alloc((size_t)MPAD * 4);
  int* seg = (int*)alloc(16 * 4);
  int* fill_cnt = (int*)alloc(8 * 4);
  int* cnt_slots = (int*)alloc(64 * 8 * 4);
  float* psum_slots = (float*)alloc(64 * 8 * 4);
  float* zsum_slots = (float*)alloc(64 * 4);
  uint16_t* pairbuf = (uint16_t*)alloc((size_t)TOKENS * 2 * HDIM * 2);
  uint16_t* wgT = (uint16_t*)alloc((size_t)NEXP * HDIM * IDIM * 2);
  uint16_t* wuT = (uint16_t*)alloc((size_t)NEXP * HDIM * IDIM * 2);
  uint16_t* wdT = (uint16_t*)alloc((size_t)NEXP * IDIM * HDIM * 2);
  uint16_t* hbuf = (uint16_t*)(ws + off);
  size_t avail = (ws_size > off) ? (ws_size - off) : 0;
  long tiles_fit = (long)(avail / (128ull * IDIM * 2));
  int chunk = (tiles_fit >= MTILES) ? MTILES : (tiles_fit < 1 ? 1 : (int)tiles_fit);

  hipMemsetAsync(cnt_slots, 0, 64 * 8 * 4, stream);
  hipMemsetAsync(psum_slots, 0, 64 * 8 * 4, stream);
  hipMemsetAsync(zsum_slots, 0, 64 * 4, stream);
  hipMemsetAsync(rowtok, 0xFF, (size_t)MPAD * 4, stream);

  convert_kernel<<<dim3(1024, 24), 256, 0, stream>>>(w_gate, w_up, w_down, wgT, wuT, wdT);
  router_kernel<<<TOKENS / 4, 256, 0, stream>>>(x, rw, xb, topw, tope,
                                                cnt_slots, psum_slots, zsum_slots);
  scan_kernel<<<1, 64, 0, stream>>>(cnt_slots, psum_slots, zsum_slots, seg, fill_cnt,
                                    out + (size_t)TOKENS * HDIM);
  fill_kernel<<<TOKENS / 256, 256, 0, stream>>>(tope, seg, fill_cnt, rowtok);

  for (int mt0 = 0; mt0 < MTILES; mt0 += chunk) {
    int ct = (MTILES - mt0 < chunk) ? (MTILES - mt0) : chunk;
    gemm1_kernel<<<dim3(IDIM / 128, ct), 256, 0, stream>>>(xb, wgT, wuT, rowtok, seg, hbuf, mt0);
    gemm2_kernel<<<dim3(HDIM / 128, ct), 256, 0, stream>>>(hbuf, wdT, rowtok, seg, pairbuf, mt0);
  }
  combine_kernel<<<(TOKENS * HDIM / 8) / 256, 256, 0, stream>>>(pairbuf, topw, out);
}

// Round 8
// 709.851 us; speedup vs baseline: 4.6194x; 1.0763x over previous
//
#include <hip/hip_runtime.h>
#include <stdint.h>

#define TOKENS 8192
#define HDIM 1024
#define IDIM 4096
#define NEXP 8
#define MPAD 17408
#define MTILES 136

typedef float f32x4 __attribute__((ext_vector_type(4)));
typedef __bf16 bf16x8 __attribute__((ext_vector_type(8)));
typedef uint32_t u32x4 __attribute__((ext_vector_type(4)));

static __device__ __forceinline__ uint16_t f2bf(float f) {
  uint32_t u = __builtin_bit_cast(uint32_t, f);
  return (uint16_t)((u + 0x7fffu + ((u >> 16) & 1u)) >> 16);
}
static __device__ __forceinline__ uint32_t pack2(float a, float b) {
  return (uint32_t)f2bf(a) | ((uint32_t)f2bf(b) << 16);
}
static __device__ __forceinline__ float bf2f(uint32_t h) {
  return __builtin_bit_cast(float, h << 16);
}
#define SWZ4(r) (((r) >> 1) & 3u)
static __device__ __forceinline__ void load_lds16(const void* g, void* l) {
  __builtin_amdgcn_global_load_lds(
      (const __attribute__((address_space(1))) uint32_t*)(uintptr_t)g,
      (__attribute__((address_space(3))) uint32_t*)(uintptr_t)l, 16, 0, 0);
}
static __device__ __forceinline__ bf16x8 rdfrag(const char* base, uint32_t row, uint32_t g) {
  return *(const bf16x8*)(base + row * 64 + ((g ^ SWZ4(row)) * 16));
}
static __device__ __forceinline__ void nt_store4(void* p, u32x4 v) {
  __builtin_nontemporal_store(v, (u32x4*)p);
}
#define WAITV(n) asm volatile("s_waitcnt vmcnt(" #n ")" ::: "memory")
#define WAITL0 asm volatile("s_waitcnt lgkmcnt(0)" ::: "memory")
#define BAR __builtin_amdgcn_s_barrier()
#define SCHEDB __builtin_amdgcn_sched_barrier(0)

// ---------------- router ----------------
__global__ __launch_bounds__(256) void router_kernel(
    const float* __restrict__ x, const float* __restrict__ rw,
    uint16_t* __restrict__ xb, float2* __restrict__ topw, int2* __restrict__ tope,
    int* __restrict__ cnt_slots, float* __restrict__ psum_slots, float* __restrict__ zsum_slots) {
  const int tid = threadIdx.x;
  const int lane = tid & 63, wid = tid >> 6;
  const int t = blockIdx.x * 4 + wid;

  const float* xrow = x + (size_t)t * HDIM + lane * 16;
  float xc[16];
#pragma unroll
  for (int i = 0; i < 4; ++i) {
    float4 v = *(const float4*)(xrow + i * 4);
    xc[i * 4 + 0] = fminf(fmaxf(v.x, -10.f), 10.f);
    xc[i * 4 + 1] = fminf(fmaxf(v.y, -10.f), 10.f);
    xc[i * 4 + 2] = fminf(fmaxf(v.z, -10.f), 10.f);
    xc[i * 4 + 3] = fminf(fmaxf(v.w, -10.f), 10.f);
  }
  uint4 o0, o1;
  o0.x = pack2(xc[0], xc[1]);   o0.y = pack2(xc[2], xc[3]);
  o0.z = pack2(xc[4], xc[5]);   o0.w = pack2(xc[6], xc[7]);
  o1.x = pack2(xc[8], xc[9]);   o1.y = pack2(xc[10], xc[11]);
  o1.z = pack2(xc[12], xc[13]); o1.w = pack2(xc[14], xc[15]);
  uint4* dst = (uint4*)(xb + (size_t)t * HDIM + lane * 16);
  dst[0] = o0; dst[1] = o1;

  float acc[8];
#pragma unroll
  for (int e = 0; e < 8; ++e) acc[e] = 0.f;
  const float* rwp = rw + (size_t)(lane * 16) * NEXP;
#pragma unroll
  for (int i = 0; i < 16; ++i) {
    float xi = xc[i];
    float4 a = *(const float4*)(rwp + i * 8);
    float4 b = *(const float4*)(rwp + i * 8 + 4);
    acc[0] += xi * a.x; acc[1] += xi * a.y; acc[2] += xi * a.z; acc[3] += xi * a.w;
    acc[4] += xi * b.x; acc[5] += xi * b.y; acc[6] += xi * b.z; acc[7] += xi * b.w;
  }
#pragma unroll
  for (int s = 1; s < 64; s <<= 1) {
#pragma unroll
    for (int e = 0; e < 8; ++e) acc[e] += __shfl_xor(acc[e], s);
  }

  __shared__ float sp[8]; __shared__ int sc[8]; __shared__ float sz;
  if (tid < 8) { sp[tid] = 0.f; sc[tid] = 0; }
  if (tid == 0) sz = 0.f;
  __syncthreads();

  if (lane == 0) {
    float mx = acc[0];
#pragma unroll
    for (int e = 1; e < 8; ++e) mx = fmaxf(mx, acc[e]);
    float p[8]; float s = 0.f;
#pragma unroll
    for (int e = 0; e < 8; ++e) { p[e] = expf(acc[e] - mx); s += p[e]; }
    float inv = 1.f / s;
#pragma unroll
    for (int e = 0; e < 8; ++e) p[e] *= inv;
    float lse = mx + logf(s);
    int e0 = 0; float b0 = p[0];
#pragma unroll
    for (int e = 1; e < 8; ++e) if (p[e] > b0) { b0 = p[e]; e0 = e; }
    int e1 = (e0 == 0) ? 1 : 0; float b1 = (e0 == 0) ? p[1] : p[0];
#pragma unroll
    for (int e = 0; e < 8; ++e) if (e != e0 && p[e] > b1) { b1 = p[e]; e1 = e; }
    float wn = 1.f / (b0 + b1);
    topw[t] = make_float2(b0 * wn, b1 * wn);
    tope[t] = make_int2(e0, e1);
#pragma unroll
    for (int e = 0; e < 8; ++e) atomicAdd(&sp[e], p[e]);
    atomicAdd(&sc[e0], 1); atomicAdd(&sc[e1], 1);
    atomicAdd(&sz, lse * lse);
  }
  __syncthreads();
  int slot = blockIdx.x & 63;
  if (tid < 8) {
    atomicAdd(&cnt_slots[slot * 8 + tid], sc[tid]);
    atomicAdd(&psum_slots[slot * 8 + tid], sp[tid]);
  }
  if (tid == 0) atomicAdd(&zsum_slots[slot], sz);
}

// ---------------- scan ----------------
__global__ void scan_kernel(const int* __restrict__ cnt_slots,
                            const float* __restrict__ psum_slots,
                            const float* __restrict__ zsum_slots,
                            int* __restrict__ seg, int* __restrict__ fill_cnt,
                            float* __restrict__ out_sc) {
  const int tid = threadIdx.x;
  __shared__ int c[8]; __shared__ float ps[8];
  if (tid < 8) {
    int s = 0; float f = 0.f;
    for (int k = 0; k < 64; ++k) { s += cnt_slots[k * 8 + tid]; f += psum_slots[k * 8 + tid]; }
    c[tid] = s; ps[tid] = f; fill_cnt[tid] = 0;
  }
  __syncthreads();
  if (tid == 0) {
    int off = 0;
    for (int e = 0; e < 8; ++e) { seg[e] = off; off += (c[e] + 127) & ~127; }
    seg[8] = off;
    float lb = 0.f;
    for (int e = 0; e < 8; ++e)
      lb += ((float)c[e] / (2.0f * (float)TOKENS)) * (ps[e] / (float)TOKENS);
    lb *= 0.001f * (float)NEXP;
    float z = 0.f;
    for (int k = 0; k < 64; ++k) z += zsum_slots[k];
    out_sc[0] = lb;
    out_sc[1] = z / (float)TOKENS;
  }
}

// ---------------- fill ----------------
__global__ __launch_bounds__(256) void fill_kernel(
    const int2* __restrict__ tope, const int* __restrict__ seg,
    int* __restrict__ fill_cnt, int* __restrict__ rowtok) {
  const int t = blockIdx.x * 256 + threadIdx.x;
  const int lane = threadIdx.x & 63;
  const int2 te = tope[t];
#pragma unroll
  for (int k = 0; k < 2; ++k) {
    const int e = k ? te.y : te.x;
    int pos = 0;
    for (int ee = 0; ee < 8; ++ee) {
      unsigned long long mask = __ballot(e == ee);
      if (e == ee) {
        unsigned long long below = mask & ((lane == 0) ? 0ull : (~0ull >> (64 - lane)));
        int nbelow = __popcll(below);
        int leader = __ffsll((unsigned long long)mask) - 1;
        int base = 0;
        if (lane == leader) base = atomicAdd(&fill_cnt[ee], __popcll(mask));
        base = __shfl(base, leader);
        pos = seg[ee] + base + nbelow;
      }
    }
    rowtok[pos] = t * 2 + k;
  }
}

// ---------------- convert: fp32 [R][C] -> bf16 transposed [C][R] ----------------
// 4 tiles (64x256 source region) per block; 16 independent NT loads/thread issued
// up-front to fill the BW-delay product (was 34% HBM latency-bound at 4 loads).
__global__ __launch_bounds__(256) void convert_kernel(
    const float* __restrict__ w_gate, const float* __restrict__ w_up,
    const float* __restrict__ w_down, uint16_t* __restrict__ wgT,
    uint16_t* __restrict__ wuT, uint16_t* __restrict__ wdT) {
  __shared__ uint64_t tt4[4][64][17];
  const int tid = threadIdx.x;
  const int z = blockIdx.y;
  const int bx = blockIdx.x;
  const float* src; uint16_t* dst; int R, C, tr, tq;
  if (z < 16) {
    R = 1024; C = 4096; tr = bx >> 4; tq = bx & 15;
    int e = z & 7;
    src = (z < 8 ? w_gate : w_up) + (size_t)e * 1024 * 4096;
    dst = (z < 8 ? wgT : wuT) + (size_t)e * 1024 * 4096;
  } else {
    R = 4096; C = 1024; tr = bx >> 2; tq = bx & 3;
    int e = z - 16;
    src = w_down + (size_t)e * 4096 * 1024;
    dst = wdT + (size_t)e * 4096 * 1024;
  }
  const int i = tid >> 4, j = tid & 15;
  const float* sb = src + (size_t)(tr * 64 + 4 * i) * C + tq * 256 + 4 * j;
  f32x4 v[4][4];
#pragma unroll
  for (int t4 = 0; t4 < 4; ++t4)
#pragma unroll
    for (int r = 0; r < 4; ++r)
      v[t4][r] = __builtin_nontemporal_load((const f32x4*)(sb + (size_t)r * C + t4 * 64));
#pragma unroll
  for (int t4 = 0; t4 < 4; ++t4)
#pragma unroll
    for (int k = 0; k < 4; ++k)
      tt4[t4][4 * j + k][i] =
          (uint64_t)pack2(v[t4][0][k], v[t4][1][k]) |
          ((uint64_t)pack2(v[t4][2][k], v[t4][3][k]) << 32);
  __syncthreads();
#pragma unroll
  for (int t4 = 0; t4 < 4; ++t4)
#pragma unroll
    for (int it = 0; it < 2; ++it) {
      int idx = it * 256 + tid;
      int c = idx >> 3, h = idx & 7;
      uint64_t a = tt4[t4][c][2 * h], b = tt4[t4][c][2 * h + 1];
      u32x4 w;
      w[0] = (uint32_t)a; w[1] = (uint32_t)(a >> 32);
      w[2] = (uint32_t)b; w[3] = (uint32_t)(b >> 32);
      nt_store4(dst + (size_t)(tq * 256 + t4 * 64 + c) * R + tr * 64 + h * 8, w);
    }
}

static __device__ __forceinline__ int xcd_swz(int b, int nwg) {
  int q = nwg >> 3, r = nwg & 7;
  int xcd = b & 7;
  int base = (xcd < r) ? xcd * (q + 1) : r * (q + 1) + (xcd - r) * q;
  return base + (b >> 3);
}

// ---------------- gemm1: h = silu(x@wg) * (x@wu); BK=32 depth-2 counted-vmcnt ----------------
__global__ __launch_bounds__(256, 2) void gemm1_kernel(
    const uint16_t* __restrict__ xb, const uint16_t* __restrict__ wgT,
    const uint16_t* __restrict__ wuT, const int* __restrict__ rowtok,
    const int* __restrict__ seg, uint16_t* __restrict__ hbuf, int mt0) {
  __shared__ __align__(16) char smem[49152];
  const int tid = threadIdx.x;
  const int lane = tid & 63, wid = tid >> 6;
  const int ct = (int)gridDim.y;
  const int b = (int)(blockIdx.y * gridDim.x + blockIdx.x);
  const int wg_lin = xcd_swz(b, 32 * ct);
  const int iblk = wg_lin / ct;
  const int mrel = wg_lin % ct;
  const int mtile = mt0 + mrel;
  const int row0 = mtile * 128;
  if (row0 >= seg[8]) return;
  int e = 0;
  while (row0 >= seg[e + 1]) ++e;
  const uint16_t* wgp = wgT + (size_t)e * HDIM * IDIM;
  const uint16_t* wup = wuT + (size_t)e * HDIM * IDIM;
  const int icol0 = iblk * 128;

  const uint32_t r0 = (uint32_t)(wid * 32 + (lane >> 2));
  const uint32_t r1 = r0 + 16;
  const uint32_t cc0 = ((lane & 3u) ^ SWZ4(r0)) * 16;
  const uint32_t cc1 = ((lane & 3u) ^ SWZ4(r1)) * 16;
  int rt0 = rowtok[row0 + r0]; int tok0 = (rt0 < 0) ? 0 : (rt0 >> 1);
  int rt1 = rowtok[row0 + r1]; int tok1 = (rt1 < 0) ? 0 : (rt1 >> 1);
  const uintptr_t a0 = (uintptr_t)(xb + (size_t)tok0 * HDIM) + cc0;
  const uintptr_t a1 = (uintptr_t)(xb + (size_t)tok1 * HDIM) + cc1;
  const uintptr_t g0 = (uintptr_t)(wgp + (size_t)(icol0 + r0) * HDIM) + cc0;
  const uintptr_t g1 = (uintptr_t)(wgp + (size_t)(icol0 + r1) * HDIM) + cc1;
  const uintptr_t u0 = (uintptr_t)(wup + (size_t)(icol0 + r0) * HDIM) + cc0;
  const uintptr_t u1 = (uintptr_t)(wup + (size_t)(icol0 + r1) * HDIM) + cc1;
  const uint32_t ldsA = (uint32_t)(wid * 2048);

  f32x4 accg[4][4] = {}; f32x4 accu[4][4] = {};

#define G1_ISSUE(t, buf)                                                        \
  {                                                                             \
    char* B_ = smem + (buf) * 24576;                                            \
    size_t o_ = (size_t)(t) * 64;                                               \
    load_lds16((const void*)(a0 + o_), B_ + ldsA);                              \
    load_lds16((const void*)(a1 + o_), B_ + ldsA + 1024);                       \
    load_lds16((const void*)(g0 + o_), B_ + 8192 + ldsA);                       \
    load_lds16((const void*)(g1 + o_), B_ + 8192 + ldsA + 1024);                \
    load_lds16((const void*)(u0 + o_), B_ + 16384 + ldsA);                      \
    load_lds16((const void*)(u1 + o_), B_ + 16384 + ldsA + 1024);               \
  }

  const uint32_t g = lane >> 4, l15 = lane & 15;
  const uint32_t mrow = (uint32_t)((wid >> 1) * 64) + l15;
  const uint32_t nrow = (uint32_t)((wid & 1) * 64) + l15;

#define G1_PHASE(buf)                                                           \
  {                                                                             \
    const char* B_ = smem + (buf) * 24576;                                      \
    bf16x8 af[4], bg[4], bu[4];                                                 \
    _Pragma("unroll") for (int mi = 0; mi < 4; ++mi)                            \
        af[mi] = rdfrag(B_, mrow + mi * 16, g);                                 \
    _Pragma("unroll") for (int ni = 0; ni < 4; ++ni) {                          \
      bg[ni] = rdfrag(B_ + 8192, nrow + ni * 16, g);                            \
      bu[ni] = rdfrag(B_ + 16384, nrow + ni * 16, g);                           \
    }                                                                           \
    WAITL0; SCHEDB;                                                             \
    BAR; SCHEDB;                                                                \
    ISSUE_NEXT;                                                                 \
    SCHEDB;                                                                     \
    __builtin_amdgcn_s_setprio(1);                                              \
    _Pragma("unroll") for (int mi = 0; mi < 4; ++mi)                            \
        _Pragma("unroll") for (int ni = 0; ni < 4; ++ni) {                      \
      accg[mi][ni] = __builtin_amdgcn_mfma_f32_16x16x32_bf16(af[mi], bg[ni], accg[mi][ni], 0, 0, 0); \
      accu[mi][ni] = __builtin_amdgcn_mfma_f32_16x16x32_bf16(af[mi], bu[ni], accu[mi][ni], 0, 0, 0); \
    }                                                                           \
    __builtin_amdgcn_s_setprio(0);                                              \
  }

  const int NT = HDIM / 32;  // 32
  WAITV(0);
  G1_ISSUE(0, 0);
  G1_ISSUE(1, 1);
  for (int t = 0; t < NT - 1; ++t) {
    WAITV(6); BAR; SCHEDB;
#define ISSUE_NEXT if (t + 2 < NT) G1_ISSUE(t + 2, t & 1)
    G1_PHASE(t & 1);
#undef ISSUE_NEXT
  }
  {
    WAITV(0); BAR; SCHEDB;
#define ISSUE_NEXT
    G1_PHASE((NT - 1) & 1);
#undef ISSUE_NEXT
  }

  __syncthreads();
  uint16_t* epi = (uint16_t*)smem;
  const int wr = wid >> 1, wc = wid & 1;
#pragma unroll
  for (int mi = 0; mi < 4; ++mi)
#pragma unroll
    for (int ni = 0; ni < 4; ++ni)
#pragma unroll
      for (int r = 0; r < 4; ++r) {
        float gv = accg[mi][ni][r], uv = accu[mi][ni][r];
        float hv = gv * uv * __frcp_rn(1.0f + __expf(-gv));
        int m = wr * 64 + mi * 16 + (lane >> 4) * 4 + r;
        int n = wc * 64 + ni * 16 + (lane & 15);
        epi[m * 136 + n] = f2bf(hv);
      }
  __syncthreads();
  const int hrow0 = (mtile - mt0) * 128;
  const int m = tid >> 1;
#pragma unroll
  for (int j = 0; j < 8; ++j) {
    int ch = (tid & 1) + j * 2;
    uint4 v = *(const uint4*)(smem + m * 272 + ch * 16);
    *(uint4*)(hbuf + ((size_t)(hrow0 + m)) * IDIM + icol0 + ch * 8) = v;
  }
}

// ---------------- gemm2: pair = h @ wd; BK=32 depth-2 counted-vmcnt ----------------
__global__ __launch_bounds__(256, 2) void gemm2_kernel(
    const uint16_t* __restrict__ hbuf, const uint16_t* __restrict__ wdT,
    const int* __restrict__ rowtok, const int* __restrict__ seg,
    uint16_t* __restrict__ pairbuf, int mt0) {
  __shared__ __align__(16) char smem[34816];
  const int tid = threadIdx.x;
  const int lane = tid & 63, wid = tid >> 6;
  const int ct = (int)gridDim.y;
  const int b = (int)(blockIdx.y * gridDim.x + blockIdx.x);
  const int wg_lin = xcd_swz(b, 8 * ct);
  const int nblk = wg_lin / ct;
  const int mrel = wg_lin % ct;
  const int mtile = mt0 + mrel;
  const int row0 = mtile * 128;
  if (row0 >= seg[8]) return;
  int e = 0;
  while (row0 >= seg[e + 1]) ++e;
  const uint16_t* wdp = wdT + (size_t)e * IDIM * HDIM;
  const int ncol0 = nblk * 128;
  const int hrow0 = (mtile - mt0) * 128;

  const uint32_t r0 = (uint32_t)(wid * 32 + (lane >> 2));
  const uint32_t r1 = r0 + 16;
  const uint32_t cc0 = ((lane & 3u) ^ SWZ4(r0)) * 16;
  const uint32_t cc1 = ((lane & 3u) ^ SWZ4(r1)) * 16;
  const uintptr_t a0 = (uintptr_t)(hbuf + (size_t)(hrow0 + r0) * IDIM) + cc0;
  const uintptr_t a1 = (uintptr_t)(hbuf + (size_t)(hrow0 + r1) * IDIM) + cc1;
  const uintptr_t b0 = (uintptr_t)(wdp + (size_t)(ncol0 + r0) * IDIM) + cc0;
  const uintptr_t b1 = (uintptr_t)(wdp + (size_t)(ncol0 + r1) * IDIM) + cc1;
  const uint32_t ldsA = (uint32_t)(wid * 2048);

  f32x4 acc[4][4] = {};

#define G2_ISSUE(t, buf)                                                        \
  {                                                                             \
    char* B_ = smem + (buf) * 16384;                                            \
    size_t o_ = (size_t)(t) * 64;                                               \
    load_lds16((const void*)(a0 + o_), B_ + ldsA);                              \
    load_lds16((const void*)(a1 + o_), B_ + ldsA + 1024);                       \
    load_lds16((const void*)(b0 + o_), B_ + 8192 + ldsA);                       \
    load_lds16((const void*)(b1 + o_), B_ + 8192 + ldsA + 1024);                \
  }

  const uint32_t g = lane >> 4, l15 = lane & 15;
  const uint32_t mrow = (uint32_t)((wid >> 1) * 64) + l15;
  const uint32_t nrow = (uint32_t)((wid & 1) * 64) + l15;

#define G2_PHASE(buf)                                                           \
  {                                                                             \
    const char* B_ = smem + (buf) * 16384;                                      \
    bf16x8 af[4], bf[4];                                                        \
    _Pragma("unroll") for (int mi = 0; mi < 4; ++mi)                            \
        af[mi] = rdfrag(B_, mrow + mi * 16, g);                                 \
    _Pragma("unroll") for (int ni = 0; ni < 4; ++ni)                            \
        bf[ni] = rdfrag(B_ + 8192, nrow + ni * 16, g);                          \
    WAITL0; SCHEDB;                                                             \
    BAR; SCHEDB;                                                                \
    ISSUE_NEXT;                                                                 \
    SCHEDB;                                                                     \
    __builtin_amdgcn_s_setprio(1);                                              \
    _Pragma("unroll") for (int mi = 0; mi < 4; ++mi)                            \
        _Pragma("unroll") for (int ni = 0; ni < 4; ++ni)                        \
            acc[mi][ni] = __builtin_amdgcn_mfma_f32_16x16x32_bf16(af[mi], bf[ni], acc[mi][ni], 0, 0, 0); \
    __builtin_amdgcn_s_setprio(0);                                              \
  }

  const int NT = IDIM / 32;  // 128
  WAITV(0);
  G2_ISSUE(0, 0);
  G2_ISSUE(1, 1);
  for (int t = 0; t < NT - 1; ++t) {
    WAITV(4); BAR; SCHEDB;
#define ISSUE_NEXT if (t + 2 < NT) G2_ISSUE(t + 2, t & 1)
    G2_PHASE(t & 1);
#undef ISSUE_NEXT
  }
  {
    WAITV(0); BAR; SCHEDB;
#define ISSUE_NEXT
    G2_PHASE((NT - 1) & 1);
#undef ISSUE_NEXT
  }

  __syncthreads();
  uint16_t* epi = (uint16_t*)smem;
  const int wr = wid >> 1, wc = wid & 1;
#pragma unroll
  for (int mi = 0; mi < 4; ++mi)
#pragma unroll
    for (int ni = 0; ni < 4; ++ni)
#pragma unroll
      for (int r = 0; r < 4; ++r) {
        int m = wr * 64 + mi * 16 + (lane >> 4) * 4 + r;
        int n = wc * 64 + ni * 16 + (lane & 15);
        epi[m * 136 + n] = f2bf(acc[mi][ni][r]);
      }
  __syncthreads();
  const int m = tid >> 1;
  const int rt = rowtok[row0 + m];
  if (rt >= 0) {
#pragma unroll
    for (int j = 0; j < 8; ++j) {
      int ch = (tid & 1) + j * 2;
      uint4 v = *(const uint4*)(smem + m * 272 + ch * 16);
      *(uint4*)(pairbuf + (size_t)rt * HDIM + ncol0 + ch * 8) = v;
    }
  }
}

// ---------------- combine ----------------
__global__ __launch_bounds__(256) void combine_kernel(
    const uint16_t* __restrict__ pairbuf, const float2* __restrict__ topw,
    float* __restrict__ out) {
  size_t i = (size_t)blockIdx.x * 256 + threadIdx.x;
  int t = (int)(i >> 7);
  int ch = (int)(i & 127);
  float2 w = topw[t];
  const uint16_t* p0 = pairbuf + (size_t)(t * 2) * HDIM + ch * 8;
  uint4 a = *(const uint4*)p0;
  uint4 b = *(const uint4*)(p0 + HDIM);
  float o[8];
  uint32_t au[4] = {a.x, a.y, a.z, a.w};
  uint32_t bu[4] = {b.x, b.y, b.z, b.w};
#pragma unroll
  for (int j = 0; j < 4; ++j) {
    float v0 = w.x * bf2f(au[j] & 0xffffu) + w.y * bf2f(bu[j] & 0xffffu);
    float v1 = w.x * bf2f(au[j] >> 16) + w.y * bf2f(bu[j] >> 16);
    o[j * 2 + 0] = fminf(fmaxf(v0, -10.f), 10.f);
    o[j * 2 + 1] = fminf(fmaxf(v1, -10.f), 10.f);
  }
  float* op = out + (size_t)t * HDIM + ch * 8;
  float4 w0 = {o[0], o[1], o[2], o[3]};
  float4 w1 = {o[4], o[5], o[6], o[7]};
  *(float4*)op = w0;
  *(float4*)(op + 4) = w1;
}

extern "C" void kernel_launch(void* const* d_in, const int* in_sizes, int n_in,
                              void* d_out, int out_size, void* d_ws, size_t ws_size,
                              hipStream_t stream) {
  (void)in_sizes; (void)n_in; (void)out_size;
  const float* x = (const float*)d_in[0];
  const float* rw = (const float*)d_in[1];
  const float* w_gate = (const float*)d_in[2];
  const float* w_up = (const float*)d_in[3];
  const float* w_down = (const float*)d_in[4];
  float* out = (float*)d_out;

  char* ws = (char*)d_ws;
  size_t off = 0;
  auto alloc = [&](size_t n) { char* p = ws + off; off += (n + 255) & ~(size_t)255; return p; };
  uint16_t* xb = (uint16_t*)alloc((size_t)TOKENS * HDIM * 2);
  float2* topw = (float2*)alloc((size_t)TOKENS * 8);
  int2* tope = (int2*)alloc((size_t)TOKENS * 8);
  int* rowtok = (int*)alloc((size_t)MPAD * 4);
  int* seg = (int*)alloc(16 * 4);
  int* fill_cnt = (int*)alloc(8 * 4);
  int* cnt_slots = (int*)alloc(64 * 8 * 4);
  float* psum_slots = (float*)alloc(64 * 8 * 4);
  float* zsum_slots = (float*)alloc(64 * 4);
  uint16_t* pairbuf = (uint16_t*)alloc((size_t)TOKENS * 2 * HDIM * 2);
  uint16_t* wgT = (uint16_t*)alloc((size_t)NEXP * HDIM * IDIM * 2);
  uint16_t* wuT = (uint16_t*)alloc((size_t)NEXP * HDIM * IDIM * 2);
  uint16_t* wdT = (uint16_t*)alloc((size_t)NEXP * IDIM * HDIM * 2);
  uint16_t* hbuf = (uint16_t*)(ws + off);
  size_t avail = (ws_size > off) ? (ws_size - off) : 0;
  long tiles_fit = (long)(avail / (128ull * IDIM * 2));
  int chunk = (tiles_fit >= MTILES) ? MTILES : (tiles_fit < 1 ? 1 : (int)tiles_fit);

  hipMemsetAsync(cnt_slots, 0, 64 * 8 * 4, stream);
  hipMemsetAsync(psum_slots, 0, 64 * 8 * 4, stream);
  hipMemsetAsync(zsum_slots, 0, 64 * 4, stream);
  hipMemsetAsync(rowtok, 0xFF, (size_t)MPAD * 4, stream);

  convert_kernel<<<dim3(256, 24), 256, 0, stream>>>(w_gate, w_up, w_down, wgT, wuT, wdT);
  router_kernel<<<TOKENS / 4, 256, 0, stream>>>(x, rw, xb, topw, tope,
                                                cnt_slots, psum_slots, zsum_slots);
  scan_kernel<<<1, 64, 0, stream>>>(cnt_slots, psum_slots, zsum_slots, seg, fill_cnt,
                                    out + (size_t)TOKENS * HDIM);
  fill_kernel<<<TOKENS / 256, 256, 0, stream>>>(tope, seg, fill_cnt, rowtok);

  for (int mt0 = 0; mt0 < MTILES; mt0 += chunk) {
    int ct = (MTILES - mt0 < chunk) ? (MTILES - mt0) : chunk;
    gemm1_kernel<<<dim3(IDIM / 128, ct), 256, 0, stream>>>(xb, wgT, wuT, rowtok, seg, hbuf, mt0);
    gemm2_kernel<<<dim3(HDIM / 128, ct), 256, 0, stream>>>(hbuf, wdT, rowtok, seg, pairbuf, mt0);
  }
  combine_kernel<<<(TOKENS * HDIM / 8) / 256, 256, 0, stream>>>(pairbuf, topw, out);
}